// Round 1
// 408.146 us; speedup vs baseline: 1.0631x; 1.0631x over previous
//
#include <hip/hip_runtime.h>

// Problem constants (fixed by the reference): B=4, S=2048, D=DK=1024.
constexpr int Bc  = 4;
constexpr int Sc  = 2048;
constexpr int Dc  = 1024;
constexpr int DKc = 1024;
constexpr long BSc = (long)Bc * Sc;      // 8192 flattened rows of x

typedef __attribute__((ext_vector_type(8))) __bf16 bf16x8;
typedef __attribute__((ext_vector_type(4))) float  floatx4;

__device__ inline __bf16 f2bf(float f) {
  unsigned u = __builtin_bit_cast(unsigned, f);
  u = (u + 0x7FFFu + ((u >> 16) & 1u)) >> 16;      // RNE
  unsigned short s = (unsigned short)u;
  return __builtin_bit_cast(__bf16, s);
}
__device__ inline float bf2f(__bf16 h) {
  unsigned u = ((unsigned)__builtin_bit_cast(unsigned short, h)) << 16;
  return __builtin_bit_cast(float, u);
}

// async global->LDS, 16B per lane. lds base must be wave-uniform; HW scatters
// lane i's 16B to ldsbase + i*16.
__device__ inline void stage16(const __bf16* g, __bf16* l) {
  __builtin_amdgcn_global_load_lds(
      (const __attribute__((address_space(1))) unsigned int*)g,
      (__attribute__((address_space(3))) unsigned int*)l, 16, 0, 0);
}

// ---------------------------------------------------------------------------
// prep: fp32->bf16 hi/lo splits for x (32768 blks), WQ (4096), WK (4096),
// plus WV transpose (hi only; 1024 blks). One dispatch (round-7).
// ---------------------------------------------------------------------------
__global__ __launch_bounds__(256) void prep(
    const float* __restrict__ x,  __bf16* __restrict__ xhi, __bf16* __restrict__ xlo,
    const float* __restrict__ wq, __bf16* __restrict__ qhi, __bf16* __restrict__ qlo,
    const float* __restrict__ wk, __bf16* __restrict__ khi, __bf16* __restrict__ klo,
    const float* __restrict__ wv, __bf16* __restrict__ vthi) {
  __shared__ float tile[32][33];
  long blk = blockIdx.x;
  if (blk >= 40960) {                 // WV transpose: Wt[dk][d] = W[d][dk]
    int t   = (int)(blk - 40960);
    int bx  = t & 31, by = t >> 5;
    int thx = threadIdx.x & 31, thy = threadIdx.x >> 5;   // 32 x 8
    int xI  = bx * 32 + thx, yI = by * 32 + thy;
#pragma unroll
    for (int j = 0; j < 32; j += 8)
      tile[thy + j][thx] = wv[(long)(yI + j) * DKc + xI];
    __syncthreads();
    int xO = by * 32 + thx, yO = bx * 32 + thy;
#pragma unroll
    for (int j = 0; j < 32; j += 8)
      vthi[(long)(yO + j) * Dc + xO] = f2bf(tile[thx][thy + j]);
    return;
  }
  const float* in; __bf16 *hi, *lo; long base;
  if (blk < 32768)      { in = x;  hi = xhi; lo = xlo; base = blk * 256; }
  else if (blk < 36864) { in = wq; hi = qhi; lo = qlo; base = (blk - 32768) * 256; }
  else                  { in = wk; hi = khi; lo = klo; base = (blk - 36864) * 256; }
  long i = base + threadIdx.x;
  float f = in[i];
  __bf16 h = f2bf(f);
  hi[i] = h;
  lo[i] = f2bf(f - bf2f(h));
}

// ---------------------------------------------------------------------------
// Shared m97-structure NT MFMA GEMM body (kept for QK / V / PV modes).
// ---------------------------------------------------------------------------
enum { MODE_QK = 0, MODE_V = 1, MODE_S = 2, MODE_PV = 3 };
constexpr int VSTR = 136;   // padded stride for the V transpose epilogue

template <int MODE>
__device__ __forceinline__ void gemm_body(
    char* smem,
    const __bf16* __restrict__ Ahi, const __bf16* __restrict__ Alo,
    const __bf16* __restrict__ Bhi, const __bf16* __restrict__ Blo,
    float* __restrict__ Cf, __bf16* __restrict__ Chi, __bf16* __restrict__ Clo,
    float* __restrict__ Pmax, float* __restrict__ Psum,
    const float* __restrict__ Ffac, float scale) {
  constexpr bool SPLIT = (MODE == MODE_QK || MODE == MODE_S);
  constexpr int  K = (MODE == MODE_PV) ? Sc : Dc;
  constexpr int  N = (MODE == MODE_S) ? Sc : DKc;
  constexpr long aBatch = (MODE == MODE_S) ? (long)Sc * DKc
                        : (MODE == MODE_PV) ? (long)Sc * Sc : 0;
  constexpr long bBatch = (MODE == MODE_S) ? (long)Sc * DKc
                        : (MODE == MODE_PV) ? (long)DKc * Sc : 0;
  constexpr long cBatch = (MODE == MODE_S) ? (long)Sc * Sc
                        : (MODE == MODE_PV) ? (long)Sc * DKc : 0;
  __bf16* sAh = (__bf16*)smem;           // [128][32] (chunk-swizzled)
  __bf16* sBh = sAh + 128 * 32;
  __bf16* sAl = sBh + 128 * 32;          // split only
  __bf16* sBl = sAl + 128 * 32;

  const int b    = blockIdx.z;
  const int wave = threadIdx.x >> 6;
  const int lane = threadIdx.x & 63;
  const int wm   = wave >> 1;            // 0..1
  const int wn   = wave & 1;             // 0..1
  const int m0   = blockIdx.y * 128;
  const int n0   = blockIdx.x * 128;

  const __bf16* Ab  = Ahi + (long)b * aBatch + (long)m0 * K;
  const __bf16* Bb  = Bhi + (long)b * bBatch + (long)n0 * K;
  const __bf16* Abl = SPLIT ? Alo + (long)b * aBatch + (long)m0 * K : nullptr;
  const __bf16* Bbl = SPLIT ? Blo + (long)b * bBatch + (long)n0 * K : nullptr;
  // ffac q-tiles are 256 rows wide now (gemm_s2): tile = blockIdx.y>>1.
  const float*  Fb  = (MODE == MODE_PV)
                    ? Ffac + ((long)b * 8 + (blockIdx.y >> 1)) * Sc : nullptr;

  const int sr   = lane >> 2;                       // 0..15
  const int sc_  = lane & 3;                        // 0..3
  const int scol = (sc_ ^ ((sr >> 1) & 3)) * 8;     // swizzled global col

  floatx4 acc[4][4];
  const floatx4 zero = {0.f, 0.f, 0.f, 0.f};
#pragma unroll
  for (int i = 0; i < 4; ++i)
#pragma unroll
    for (int j = 0; j < 4; ++j) acc[i][j] = zero;

  const int frow = lane & 15;
  const int pko = ((lane >> 4) ^ ((frow >> 1) & 3)) * 8;

#pragma unroll 1
  for (int k0 = 0; k0 < K; k0 += 32) {
    if constexpr (MODE == MODE_PV) {
#pragma unroll
      for (int i = 0; i < 2; ++i) {
        const int rb = wave * 32 + i * 16;
        stage16(Bb + (long)(rb + sr) * K + k0 + scol, sBh + rb * 32);
      }
      const int tr = threadIdx.x >> 2;              // 0..63
      const int pc = threadIdx.x & 3;               // physical chunk
#pragma unroll
      for (int h = 0; h < 2; ++h) {
        int r  = h * 64 + tr;
        int lc = pc ^ ((r >> 1) & 3);               // logical chunk
        bf16x8 pv = *(const bf16x8*)(Ab + (long)r * K + k0 + lc * 8);
        const float* fp = Fb + k0 + lc * 8;
        bf16x8 o;
#pragma unroll
        for (int j = 0; j < 8; ++j) o[j] = f2bf(bf2f(pv[j]) * fp[j]);
        *(bf16x8*)(sAh + r * 32 + pc * 8) = o;
      }
    } else {
#pragma unroll
      for (int i = 0; i < 2; ++i) {
        const int rb = wave * 32 + i * 16;          // wave-uniform row base
        const long go = (long)(rb + sr) * K + k0 + scol;
        stage16(Ab + go, sAh + rb * 32);
        stage16(Bb + go, sBh + rb * 32);
        if constexpr (SPLIT) {
          stage16(Abl + go, sAl + rb * 32);
          stage16(Bbl + go, sBl + rb * 32);
        }
      }
    }
    __syncthreads();

    bf16x8 af[4], bfr[4], afl[4], bfl[4];
#pragma unroll
    for (int t = 0; t < 4; ++t) {
      af[t]  = *(const bf16x8*)(sAh + (wm * 64 + t * 16 + frow) * 32 + pko);
      bfr[t] = *(const bf16x8*)(sBh + (wn * 64 + t * 16 + frow) * 32 + pko);
      if constexpr (SPLIT) {
        afl[t] = *(const bf16x8*)(sAl + (wm * 64 + t * 16 + frow) * 32 + pko);
        bfl[t] = *(const bf16x8*)(sBl + (wn * 64 + t * 16 + frow) * 32 + pko);
      }
    }
#pragma unroll
    for (int mt = 0; mt < 4; ++mt)
#pragma unroll
      for (int nt = 0; nt < 4; ++nt) {
        acc[mt][nt] = __builtin_amdgcn_mfma_f32_16x16x32_bf16(af[mt], bfr[nt], acc[mt][nt], 0, 0, 0);
        if constexpr (SPLIT) {
          acc[mt][nt] = __builtin_amdgcn_mfma_f32_16x16x32_bf16(af[mt], bfl[nt], acc[mt][nt], 0, 0, 0);
          acc[mt][nt] = __builtin_amdgcn_mfma_f32_16x16x32_bf16(afl[mt], bfr[nt], acc[mt][nt], 0, 0, 0);
        }
      }
    __syncthreads();
  }

  // Epilogue. D layout: col=lane&15, row=(lane>>4)*4+reg (m89/m91-verified).
  const int crow0 = (lane >> 4) * 4;
  const int ccol  = lane & 15;
  const int tid   = threadIdx.x;

  if constexpr (MODE == MODE_QK) {
    __bf16* sT = (__bf16*)smem;          // [128][128] bf16 = 32KB
#pragma unroll 1
    for (int pass = 0; pass < 2; ++pass) {
      __syncthreads();
#pragma unroll
      for (int nt = 0; nt < 4; ++nt) {
        int col = wn * 64 + nt * 16 + ccol;
#pragma unroll
        for (int mt = 0; mt < 4; ++mt) {
          int row = wm * 64 + mt * 16 + crow0;
#pragma unroll
          for (int r = 0; r < 4; ++r) {
            float v = acc[mt][nt][r] * scale;
            __bf16 h = f2bf(v);
            sT[(row + r) * 128 + col] = pass ? f2bf(v - bf2f(h)) : h;
          }
        }
      }
      __syncthreads();
      __bf16* dst = pass ? Clo : Chi;
#pragma unroll
      for (int c = 0; c < 8; ++c) {
        int flat = c * 2048 + tid * 8;
        int row = flat >> 7, col = flat & 127;
        *(bf16x8*)(dst + (long)(m0 + row) * N + n0 + col) = *(const bf16x8*)(sT + flat);
      }
    }
    return;
  }

  if constexpr (MODE == MODE_V) {
    __bf16* sT = (__bf16*)smem;          // [128][VSTR]
#pragma unroll
    for (int nt = 0; nt < 4; ++nt) {
      int nl = wn * 64 + nt * 16 + ccol;
#pragma unroll
      for (int mt = 0; mt < 4; ++mt) {
        int ml = wm * 64 + mt * 16 + crow0;
#pragma unroll
        for (int r = 0; r < 4; ++r)
          sT[(long)nl * VSTR + ml + r] = f2bf(acc[mt][nt][r]);
      }
    }
    __syncthreads();
    const int bb   = m0 >> 11;          // tile fully within one batch
    const int seq0 = m0 & (Sc - 1);
    __bf16* dst = Chi + (long)bb * DKc * Sc + seq0;
#pragma unroll
    for (int c = 0; c < 8; ++c) {
      int flat = c * 2048 + tid * 8;    // logical 128x128; 16B per thread
      int row = flat >> 7, col = flat & 127;
      *(bf16x8*)(dst + (long)(n0 + row) * Sc + col) =
          *(const bf16x8*)(sT + (long)row * VSTR + col);
    }
    return;
  }

  // MODE_PV: direct fp32 store.
#pragma unroll
  for (int nt = 0; nt < 4; ++nt) {
    int cn = n0 + wn * 64 + nt * 16 + ccol;
#pragma unroll
    for (int mt = 0; mt < 4; ++mt) {
#pragma unroll
      for (int r = 0; r < 4; ++r) {
        int cm_ = m0 + wm * 64 + mt * 16 + crow0 + r;
        Cf[(long)b * cBatch + (long)cm_ * N + cn] = acc[mt][nt][r] * scale;
      }
    }
  }
}

// ---------------------------------------------------------------------------
// Wrappers for the m97-structure modes.
// ---------------------------------------------------------------------------
__global__ __launch_bounds__(256) void gemm_t(
    const __bf16* __restrict__ xhi, const __bf16* __restrict__ xlo,
    const __bf16* __restrict__ gthi, const __bf16* __restrict__ gtlo,
    __bf16* __restrict__ thi, __bf16* __restrict__ tlo) {
  __shared__ __align__(16) char smem[32768];
  gemm_body<MODE_QK>(smem, xhi, xlo, gthi, gtlo, nullptr, thi, tlo,
                     nullptr, nullptr, nullptr, 1.0f);
}

__global__ __launch_bounds__(256) void gemm_v(
    const __bf16* __restrict__ xhi, const __bf16* __restrict__ wvthi,
    __bf16* __restrict__ vt) {
  __shared__ __align__(16) char smem[128 * VSTR * 2];   // 34 KB (epilogue)
  gemm_body<MODE_V>(smem, xhi, nullptr, wvthi, nullptr, nullptr, vt, nullptr,
                    nullptr, nullptr, nullptr, 1.0f);
}

__global__ __launch_bounds__(256) void gemm_pv(
    const __bf16* __restrict__ P, const __bf16* __restrict__ vt,
    float* __restrict__ out, const float* __restrict__ ffac) {
  __shared__ __align__(16) char smem[16384];
  gemm_body<MODE_PV>(smem, P, nullptr, vt, nullptr, out, nullptr, nullptr,
                     nullptr, nullptr, ffac, 1.0f);
}

// ---------------------------------------------------------------------------
// gemm_s2: S = T x^T (split, 3-MFMA) at 256x256/BK=32, 8 waves (2x4), wave
// tile 128x64. 3-phase-per-K-tile pipeline with COUNTED vmcnt (T3/T4):
//   phase A: read Ah,Bh frags (kept in regs) -> 32 MFMA Ah*Bh
//   phase B: read Bl               -> 32 MFMA Ah*Bl
//   phase C: read Al               -> 32 MFMA Al*Bh
// Each phase is the LAST LDS use of its operand region, so tile t+1/t+2
// stages land in regions freed one phase earlier; 2 LDS buffers, 8 loads
// per thread per K-tile issued (2,3,3) per phase. FIFO accounting gives
// steady-state waits vmcnt(10/10/11) -- the loop NEVER drains to 0.
// Prologue = 14 loads {Ah0,Bh0,Bl0,Al0,Ah1,Bh1,Bl1}; peeled tail waits
// (10,10,8) then (4,2,0). setprio(1) around each MFMA cluster (T5).
// ---------------------------------------------------------------------------
__device__ __forceinline__ void bar_raw() {
  asm volatile("" ::: "memory");
  __builtin_amdgcn_s_barrier();
  asm volatile("" ::: "memory");
}
template <int N>
__device__ __forceinline__ void vmwait() {
  asm volatile("s_waitcnt vmcnt(%0)" :: "n"(N));
  __builtin_amdgcn_sched_barrier(0);
}

struct SCtx {
  const __bf16 *pAh, *pAl, *pBh, *pBl;  // per-thread staging src (row+swz col)
  __bf16* lds;
  int stLds;                             // wave*32 rows * 32 elems
  int aoff, boff;                        // frag base offsets (elements)
};

template <int WA, int WB, int WC, bool SAL, bool S2A, bool S2B>
__device__ __forceinline__ void tile_step(const SCtx& c, int t,
                                          floatx4 (&acc)[8][4]) {
  constexpr int K = 1024;
  constexpr int BH = 8192, BL = 16384, AL = 24576;   // region elem offsets
  __bf16* cur = c.lds + (t & 1) * 32768;
  __bf16* oth = c.lds + ((t & 1) ^ 1) * 32768;
  bf16x8 af[8], bfr[4];

  // ---- phase A : acc += Ah * Bh ----
  vmwait<WA>();
  bar_raw();
#pragma unroll
  for (int mt = 0; mt < 8; ++mt)
    af[mt] = *(const bf16x8*)(cur + c.aoff + mt * 512);
#pragma unroll
  for (int nt = 0; nt < 4; ++nt)
    bfr[nt] = *(const bf16x8*)(cur + BH + c.boff + nt * 512);
  if (SAL) {  // stage Al_{t+1} into other buffer (its AL freed last phase)
    const __bf16* s = c.pAl + (t + 1) * 32;
    stage16(s, oth + AL + c.stLds);
    stage16(s + 16 * K, oth + AL + c.stLds + 512);
  }
  bar_raw();
  __builtin_amdgcn_s_setprio(1);
#pragma unroll
  for (int mt = 0; mt < 8; ++mt)
#pragma unroll
    for (int nt = 0; nt < 4; ++nt)
      acc[mt][nt] = __builtin_amdgcn_mfma_f32_16x16x32_bf16(af[mt], bfr[nt], acc[mt][nt], 0, 0, 0);
  __builtin_amdgcn_s_setprio(0);

  // ---- phase B : acc += Ah * Bl ----
  vmwait<WB>();
  bar_raw();
  {
    bf16x8 bfl[4];
#pragma unroll
    for (int nt = 0; nt < 4; ++nt)
      bfl[nt] = *(const bf16x8*)(cur + BL + c.boff + nt * 512);
    if (S2A) {  // Ah_{t+2} x2 + Bh_{t+2} #1 into cur (AH/BH freed in phase A)
      const __bf16* sa = c.pAh + (t + 2) * 32;
      stage16(sa, cur + c.stLds);
      stage16(sa + 16 * K, cur + c.stLds + 512);
      stage16(c.pBh + (t + 2) * 32, cur + BH + c.stLds);
    }
    bar_raw();
    __builtin_amdgcn_s_setprio(1);
#pragma unroll
    for (int mt = 0; mt < 8; ++mt)
#pragma unroll
      for (int nt = 0; nt < 4; ++nt)
        acc[mt][nt] = __builtin_amdgcn_mfma_f32_16x16x32_bf16(af[mt], bfl[nt], acc[mt][nt], 0, 0, 0);
    __builtin_amdgcn_s_setprio(0);
  }

  // ---- phase C : acc += Al * Bh ----
  vmwait<WC>();
  bar_raw();
  {
    bf16x8 afl[8];
#pragma unroll
    for (int mt = 0; mt < 8; ++mt)
      afl[mt] = *(const bf16x8*)(cur + AL + c.aoff + mt * 512);
    if (S2B) {  // Bh_{t+2} #2 + Bl_{t+2} x2 (BL freed in phase B)
      stage16(c.pBh + (t + 2) * 32 + 16 * K, cur + BH + c.stLds + 512);
      const __bf16* sb = c.pBl + (t + 2) * 32;
      stage16(sb, cur + BL + c.stLds);
      stage16(sb + 16 * K, cur + BL + c.stLds + 512);
    }
    bar_raw();
    __builtin_amdgcn_s_setprio(1);
#pragma unroll
    for (int mt = 0; mt < 8; ++mt)
#pragma unroll
      for (int nt = 0; nt < 4; ++nt)
        acc[mt][nt] = __builtin_amdgcn_mfma_f32_16x16x32_bf16(afl[mt], bfr[nt], acc[mt][nt], 0, 0, 0);
    __builtin_amdgcn_s_setprio(0);
  }
}

__global__ __launch_bounds__(512, 2) void gemm_s2(
    const __bf16* __restrict__ thi, const __bf16* __restrict__ tlo,
    const __bf16* __restrict__ xhi, const __bf16* __restrict__ xlo,
    __bf16* __restrict__ P, float* __restrict__ Pmax, float* __restrict__ Psum) {
  __shared__ __align__(16) __bf16 smem[65536];   // 128 KB: 2 x {Ah,Bh,Bl,Al}
  constexpr int K = 1024;
  const int b    = blockIdx.z;
  const int m0   = blockIdx.y * 256;
  const int n0   = blockIdx.x * 256;
  const int wave = threadIdx.x >> 6;
  const int lane = threadIdx.x & 63;
  const int wm   = wave >> 2;            // 0..1
  const int wn   = wave & 3;             // 0..3
  const int sr   = lane >> 2;
  const int scol = ((lane & 3) ^ ((sr >> 1) & 3)) * 8;   // chunk-XOR swizzle
  const int frow = lane & 15;
  const int pko  = ((lane >> 4) ^ ((frow >> 1) & 3)) * 8;

  SCtx c;
  const long batch = (long)Sc * 1024;
  const long ar = (long)(m0 + wave * 32 + sr) * K + scol;
  const long br = (long)(n0 + wave * 32 + sr) * K + scol;
  c.pAh = thi + (long)b * batch + ar;
  c.pAl = tlo + (long)b * batch + ar;
  c.pBh = xhi + (long)b * batch + br;
  c.pBl = xlo + (long)b * batch + br;
  c.lds = smem;
  c.stLds = wave * 1024;
  c.aoff = (wm * 128 + frow) * 32 + pko;
  c.boff = (wn * 64 + frow) * 32 + pko;

  // Prologue: tile0 {Ah,Bh,Bl,Al} + tile1 {Ah,Bh,Bl}. Issue ORDER is
  // load-accounting-critical (FIFO vmcnt).
  {
    __bf16* b0 = smem;
    __bf16* b1 = smem + 32768;
    stage16(c.pAh, b0 + c.stLds);               stage16(c.pAh + 16 * K, b0 + c.stLds + 512);
    stage16(c.pBh, b0 + 8192 + c.stLds);        stage16(c.pBh + 16 * K, b0 + 8192 + c.stLds + 512);
    stage16(c.pBl, b0 + 16384 + c.stLds);       stage16(c.pBl + 16 * K, b0 + 16384 + c.stLds + 512);
    stage16(c.pAl, b0 + 24576 + c.stLds);       stage16(c.pAl + 16 * K, b0 + 24576 + c.stLds + 512);
    stage16(c.pAh + 32, b1 + c.stLds);          stage16(c.pAh + 32 + 16 * K, b1 + c.stLds + 512);
    stage16(c.pBh + 32, b1 + 8192 + c.stLds);   stage16(c.pBh + 32 + 16 * K, b1 + 8192 + c.stLds + 512);
    stage16(c.pBl + 32, b1 + 16384 + c.stLds);  stage16(c.pBl + 32 + 16 * K, b1 + 16384 + c.stLds + 512);
  }

  floatx4 acc[8][4];
  const floatx4 zero = {0.f, 0.f, 0.f, 0.f};
#pragma unroll
  for (int i = 0; i < 8; ++i)
#pragma unroll
    for (int j = 0; j < 4; ++j) acc[i][j] = zero;

#pragma unroll 1
  for (int t = 0; t < 30; ++t) tile_step<10, 10, 11, true, true, true>(c, t, acc);
  tile_step<10, 10, 8, true, false, false>(c, 30, acc);
  tile_step<4, 2, 0, false, false, false>(c, 31, acc);

  // ---- epilogue: softmax-over-q partials + p = exp(s - M_t) ----
  const int crow0 = (lane >> 4) * 4;
  const int ccol  = lane & 15;
  const int tid   = threadIdx.x;
  constexpr float scale = 0.03125f;
  float* smax = (float*)smem;            // [2][256]
  float* ssum = smax + 512;              // [2][256]

  float cm[4];
#pragma unroll
  for (int nt = 0; nt < 4; ++nt) {
    float mx = -3.0e38f;
#pragma unroll
    for (int mt = 0; mt < 8; ++mt)
#pragma unroll
      for (int r = 0; r < 4; ++r) mx = fmaxf(mx, acc[mt][nt][r] * scale);
    cm[nt] = mx;
  }
#pragma unroll
  for (int off = 16; off <= 32; off <<= 1)
#pragma unroll
    for (int nt = 0; nt < 4; ++nt)
      cm[nt] = fmaxf(cm[nt], __shfl_xor(cm[nt], off, 64));
  __syncthreads();
  if (lane < 16)
#pragma unroll
    for (int nt = 0; nt < 4; ++nt)
      smax[wm * 256 + wn * 64 + nt * 16 + lane] = cm[nt];
  __syncthreads();
  float mfin[4];
#pragma unroll
  for (int nt = 0; nt < 4; ++nt) {
    int cidx = wn * 64 + nt * 16 + ccol;
    mfin[nt] = fmaxf(smax[cidx], smax[256 + cidx]);
  }
  float ps[4];
#pragma unroll
  for (int nt = 0; nt < 4; ++nt) {
    float s = 0.f;
#pragma unroll
    for (int mt = 0; mt < 8; ++mt)
#pragma unroll
      for (int r = 0; r < 4; ++r)
        s += __expf(acc[mt][nt][r] * scale - mfin[nt]);
    ps[nt] = s;
  }
#pragma unroll
  for (int off = 16; off <= 32; off <<= 1)
#pragma unroll
    for (int nt = 0; nt < 4; ++nt) ps[nt] += __shfl_xor(ps[nt], off, 64);
  if (lane < 16)
#pragma unroll
    for (int nt = 0; nt < 4; ++nt)
      ssum[wm * 256 + wn * 64 + nt * 16 + lane] = ps[nt];
  __syncthreads();
  if (tid < 256) {
    long o = ((long)b * 8 + blockIdx.y) * Sc + n0 + tid;
    Pmax[o] = fmaxf(smax[tid], smax[256 + tid]);
    Psum[o] = ssum[tid] + ssum[256 + tid];
  }
  __syncthreads();
  // p -> bf16 via bit4-5 XOR-swizzled LDS round-trip (<=2-way banks both
  // sides), then coalesced 16B stores.
  __bf16* sT = smem;                     // [256][256] = 128 KB
#pragma unroll
  for (int nt = 0; nt < 4; ++nt) {
    int col = wn * 64 + nt * 16 + ccol;
#pragma unroll
    for (int mt = 0; mt < 8; ++mt) {
      int rowb = wm * 128 + mt * 16 + crow0;
#pragma unroll
      for (int r = 0; r < 4; ++r) {
        int row = rowb + r;
        sT[row * 256 + (col ^ (((row >> 2) & 3) << 4))] =
            f2bf(__expf(acc[mt][nt][r] * scale - mfin[nt]));
      }
    }
  }
  __syncthreads();
  __bf16* Pb = P + (long)b * ((long)Sc * Sc);
#pragma unroll
  for (int cc = 0; cc < 16; ++cc) {
    int flat = cc * 4096 + tid * 8;
    int row = flat >> 8, col = flat & 255;
    *(bf16x8*)(Pb + (long)(m0 + row) * Sc + n0 + col) =
        *(const bf16x8*)(sT + row * 256 + (col ^ (((row >> 2) & 3) << 4)));
  }
}

// ---------------------------------------------------------------------------
// G GEMM, 64x64 tiles (256 blocks; round-7). Gt[m][n] = sum_k WK[m,k]WQ[n,k],
// split operands (3 MFMA), hi/lo output.
// ---------------------------------------------------------------------------
__global__ __launch_bounds__(256) void gemm_g64(
    const __bf16* __restrict__ Ahi, const __bf16* __restrict__ Alo,
    const __bf16* __restrict__ Bhi, const __bf16* __restrict__ Blo,
    __bf16* __restrict__ Chi, __bf16* __restrict__ Clo) {
  constexpr int K = Dc, N = DKc;
  __shared__ __align__(16) char smem[16384];
  __bf16* sAh = (__bf16*)smem;           // [64][32]
  __bf16* sBh = sAh + 64 * 32;
  __bf16* sAl = sBh + 64 * 32;
  __bf16* sBl = sAl + 64 * 32;

  const int wave = threadIdx.x >> 6;
  const int lane = threadIdx.x & 63;
  const int wm   = wave >> 1, wn = wave & 1;
  const int m0   = blockIdx.y * 64;
  const int n0   = blockIdx.x * 64;

  const int sr   = lane >> 2;
  const int sc_  = lane & 3;
  const int scol = (sc_ ^ ((sr >> 1) & 3)) * 8;
  const int frow = lane & 15;
  const int pko  = ((lane >> 4) ^ ((frow >> 1) & 3)) * 8;

  floatx4 acc[2][2];
  const floatx4 zero = {0.f, 0.f, 0.f, 0.f};
#pragma unroll
  for (int i = 0; i < 2; ++i)
#pragma unroll
    for (int j = 0; j < 2; ++j) acc[i][j] = zero;

#pragma unroll 1
  for (int k0 = 0; k0 < K; k0 += 32) {
    const int rb = wave * 16;                       // wave stages 16 rows
    const long ga = (long)(m0 + rb + sr) * K + k0 + scol;
    const long gb = (long)(n0 + rb + sr) * K + k0 + scol;
    stage16(Ahi + ga, sAh + rb * 32);
    stage16(Alo + ga, sAl + rb * 32);
    stage16(Bhi + gb, sBh + rb * 32);
    stage16(Blo + gb, sBl + rb * 32);
    __syncthreads();

    bf16x8 af[2], bfr[2], afl[2], bfl[2];
#pragma unroll
    for (int t = 0; t < 2; ++t) {
      af[t]  = *(const bf16x8*)(sAh + (wm * 32 + t * 16 + frow) * 32 + pko);
      bfr[t] = *(const bf16x8*)(sBh + (wn * 32 + t * 16 + frow) * 32 + pko);
      afl[t] = *(const bf16x8*)(sAl + (wm * 32 + t * 16 + frow) * 32 + pko);
      bfl[t] = *(const bf16x8*)(sBl + (wn * 32 + t * 16 + frow) * 32 + pko);
    }
#pragma unroll
    for (int mt = 0; mt < 2; ++mt)
#pragma unroll
      for (int nt = 0; nt < 2; ++nt) {
        acc[mt][nt] = __builtin_amdgcn_mfma_f32_16x16x32_bf16(af[mt], bfr[nt], acc[mt][nt], 0, 0, 0);
        acc[mt][nt] = __builtin_amdgcn_mfma_f32_16x16x32_bf16(af[mt], bfl[nt], acc[mt][nt], 0, 0, 0);
        acc[mt][nt] = __builtin_amdgcn_mfma_f32_16x16x32_bf16(afl[mt], bfr[nt], acc[mt][nt], 0, 0, 0);
      }
    __syncthreads();
  }

  const int crow0 = (lane >> 4) * 4;
  const int ccol  = lane & 15;
  const int tid   = threadIdx.x;
  __bf16* sT = (__bf16*)smem;            // [64][64] = 8KB
#pragma unroll 1
  for (int pass = 0; pass < 2; ++pass) {
    __syncthreads();
#pragma unroll
    for (int nt = 0; nt < 2; ++nt) {
      int col = wn * 32 + nt * 16 + ccol;
#pragma unroll
      for (int mt = 0; mt < 2; ++mt) {
        int row = wm * 32 + mt * 16 + crow0;
#pragma unroll
        for (int r = 0; r < 4; ++r) {
          float v = acc[mt][nt][r];
          __bf16 h = f2bf(v);
          sT[(row + r) * 64 + col] = pass ? f2bf(v - bf2f(h)) : h;
        }
      }
    }
    __syncthreads();
    __bf16* dst = pass ? Clo : Chi;
#pragma unroll
    for (int c = 0; c < 2; ++c) {
      int flat = c * 2048 + tid * 8;
      int row = flat >> 6, col = flat & 63;
      *(bf16x8*)(dst + (long)(m0 + row) * N + n0 + col) = *(const bf16x8*)(sT + flat);
    }
  }
}

// ---------------------------------------------------------------------------
// Fold 8 q-tile partials -> ffac[b][t][k] = exp(M_t - M_k) / Z_k.
// ---------------------------------------------------------------------------
__global__ __launch_bounds__(256) void softmax_reduce(const float* __restrict__ Pmax,
                                                      const float* __restrict__ Psum,
                                                      float* __restrict__ Ffac) {
  int idx = blockIdx.x * 256 + threadIdx.x;   // b*2048 + k
  int b = idx >> 11, k = idx & (Sc - 1);
  const float* pm = Pmax + (long)b * 8 * Sc + k;
  const float* ps = Psum + (long)b * 8 * Sc + k;
  float M = -3.0e38f;
#pragma unroll
  for (int t = 0; t < 8; ++t) M = fmaxf(M, pm[(long)t * Sc]);
  float S = 0.f;
#pragma unroll
  for (int t = 0; t < 8; ++t)
    S += ps[(long)t * Sc] * __expf(pm[(long)t * Sc] - M);
  float inv = 1.0f / S;
  float* fo = Ffac + (long)b * 8 * Sc + k;
#pragma unroll
  for (int t = 0; t < 8; ++t)
    fo[(long)t * Sc] = __expf(pm[(long)t * Sc] - M) * inv;
}

// ---------------------------------------------------------------------------
extern "C" void kernel_launch(void* const* d_in, const int* in_sizes, int n_in,
                              void* d_out, int out_size, void* d_ws, size_t ws_size,
                              hipStream_t stream) {
  const float* x  = (const float*)d_in[0];
  const float* WQ = (const float*)d_in[1];
  const float* WK = (const float*)d_in[2];
  const float* WV = (const float*)d_in[3];
  float* out = (float*)d_out;
  char* ws = (char*)d_ws;
  const long MB = 1024L * 1024L;

  // Workspace layout (peak ~130 MB).
  __bf16* xhi  = (__bf16*)(ws + 0 * MB);     // 16 MB
  __bf16* xlo  = (__bf16*)(ws + 16 * MB);    // 16 MB
  __bf16* wqhi = (__bf16*)(ws + 32 * MB);    // 2 MB each (element-wise split)
  __bf16* wqlo = (__bf16*)(ws + 34 * MB);
  __bf16* wkhi = (__bf16*)(ws + 36 * MB);
  __bf16* wklo = (__bf16*)(ws + 38 * MB);
  __bf16* wvthi= (__bf16*)(ws + 40 * MB);    // transposed, hi only
  __bf16* gthi = (__bf16*)(ws + 44 * MB);    // 2 MB each: Gt = (WQ WK^T)^T
  __bf16* gtlo = (__bf16*)(ws + 46 * MB);
  __bf16* thi  = (__bf16*)(ws + 48 * MB);    // 16 MB each: T = x*G
  __bf16* tlo  = (__bf16*)(ws + 64 * MB);
  __bf16* vt   = (__bf16*)(ws + 80 * MB);    // 16 MB, [B][DK][S]
  __bf16* P    = (__bf16*)(ws + 96 * MB);    // 32 MB, p = exp(s - M_t), bf16
  float*  pmax = (float*)(ws + 128 * MB);    // [B][8][S]
  float*  psum = (float*)(ws + 129 * MB);
  float*  ffac = (float*)(ws + 130 * MB);    // [B][8][S]

  // 1. casts + WV transpose (one dispatch)
  prep<<<41984, 256, 0, stream>>>(x, xhi, xlo, WQ, wqhi, wqlo, WK, wkhi, wklo,
                                  WV, wvthi);

  // 2. Gt[d][a] = G[a][d]: NT(A=WK, B=WQ), 64x64 tiles -> 256 blocks.
  gemm_g64<<<dim3(16, 16), 256, 0, stream>>>(wkhi, wklo, wqhi, wqlo, gthi, gtlo);

  // 3. T = x*G (split).
  gemm_t<<<dim3(DKc / 128, BSc / 128, 1), 256, 0, stream>>>(
      xhi, xlo, gthi, gtlo, thi, tlo);

  // 4. Vt = (x*WV)^T per batch (plain).
  gemm_v<<<dim3(DKc / 128, BSc / 128, 1), 256, 0, stream>>>(xhi, wvthi, vt);

  // 5. S = T*x^T * scale; emits p (bf16) + per-256-tile column max/expsum.
  //    256^2 tile pipeline: 256 blocks = 1/CU, 512 threads, 128 KB LDS.
  gemm_s2<<<dim3(Sc / 256, Sc / 256, Bc), 512, 0, stream>>>(
      thi, tlo, xhi, xlo, P, pmax, psum);

  // 6. partials -> ffac (8 q-tiles now)
  softmax_reduce<<<32, 256, 0, stream>>>(pmax, psum, ffac);

  // 7. out = (p .* ffac) @ Vt^T — apply fused into A-staging.
  gemm_pv<<<dim3(DKc / 128, Sc / 128, Bc), 256, 0, stream>>>(P, vt, out, ffac);
}

// Round 2
// 359.022 us; speedup vs baseline: 1.2085x; 1.1368x over previous
//
#include <hip/hip_runtime.h>

// Problem constants (fixed by the reference): B=4, S=2048, D=DK=1024.
constexpr int Bc  = 4;
constexpr int Sc  = 2048;
constexpr int Dc  = 1024;
constexpr int DKc = 1024;
constexpr long BSc = (long)Bc * Sc;      // 8192 flattened rows of x

typedef __attribute__((ext_vector_type(8))) __bf16 bf16x8;
typedef __attribute__((ext_vector_type(4))) float  floatx4;

__device__ inline __bf16 f2bf(float f) {
  unsigned u = __builtin_bit_cast(unsigned, f);
  u = (u + 0x7FFFu + ((u >> 16) & 1u)) >> 16;      // RNE
  unsigned short s = (unsigned short)u;
  return __builtin_bit_cast(__bf16, s);
}
__device__ inline float bf2f(__bf16 h) {
  unsigned u = ((unsigned)__builtin_bit_cast(unsigned short, h)) << 16;
  return __builtin_bit_cast(float, u);
}

// async global->LDS, 16B per lane. lds base must be wave-uniform; HW scatters
// lane i's 16B to ldsbase + i*16.
__device__ inline void stage16(const __bf16* g, __bf16* l) {
  __builtin_amdgcn_global_load_lds(
      (const __attribute__((address_space(1))) unsigned int*)g,
      (__attribute__((address_space(3))) unsigned int*)l, 16, 0, 0);
}

__device__ __forceinline__ void bar_raw() {
  asm volatile("" ::: "memory");
  __builtin_amdgcn_s_barrier();
  asm volatile("" ::: "memory");
}
template <int N>
__device__ __forceinline__ void vmwait() {
  asm volatile("s_waitcnt vmcnt(%0)" :: "n"(N));
  __builtin_amdgcn_sched_barrier(0);
}

// ---------------------------------------------------------------------------
// prep: fp32->bf16 hi/lo splits for x (32768 blks), WQ (4096), WK (4096),
// plus WV transpose (hi only; 1024 blks). One dispatch (round-7).
// ---------------------------------------------------------------------------
__global__ __launch_bounds__(256) void prep(
    const float* __restrict__ x,  __bf16* __restrict__ xhi, __bf16* __restrict__ xlo,
    const float* __restrict__ wq, __bf16* __restrict__ qhi, __bf16* __restrict__ qlo,
    const float* __restrict__ wk, __bf16* __restrict__ khi, __bf16* __restrict__ klo,
    const float* __restrict__ wv, __bf16* __restrict__ vthi) {
  __shared__ float tile[32][33];
  long blk = blockIdx.x;
  if (blk >= 40960) {                 // WV transpose: Wt[dk][d] = W[d][dk]
    int t   = (int)(blk - 40960);
    int bx  = t & 31, by = t >> 5;
    int thx = threadIdx.x & 31, thy = threadIdx.x >> 5;   // 32 x 8
    int xI  = bx * 32 + thx, yI = by * 32 + thy;
#pragma unroll
    for (int j = 0; j < 32; j += 8)
      tile[thy + j][thx] = wv[(long)(yI + j) * DKc + xI];
    __syncthreads();
    int xO = by * 32 + thx, yO = bx * 32 + thy;
#pragma unroll
    for (int j = 0; j < 32; j += 8)
      vthi[(long)(yO + j) * Dc + xO] = f2bf(tile[thx][thy + j]);
    return;
  }
  const float* in; __bf16 *hi, *lo; long base;
  if (blk < 32768)      { in = x;  hi = xhi; lo = xlo; base = blk * 256; }
  else if (blk < 36864) { in = wq; hi = qhi; lo = qlo; base = (blk - 32768) * 256; }
  else                  { in = wk; hi = khi; lo = klo; base = (blk - 36864) * 256; }
  long i = base + threadIdx.x;
  float f = in[i];
  __bf16 h = f2bf(f);
  hi[i] = h;
  lo[i] = f2bf(f - bf2f(h));
}

// ---------------------------------------------------------------------------
// Shared m97-structure NT MFMA GEMM body (kept for V / PV modes).
// ---------------------------------------------------------------------------
enum { MODE_QK = 0, MODE_V = 1, MODE_S = 2, MODE_PV = 3 };
constexpr int VSTR = 136;   // padded stride for the V transpose epilogue

template <int MODE>
__device__ __forceinline__ void gemm_body(
    char* smem,
    const __bf16* __restrict__ Ahi, const __bf16* __restrict__ Alo,
    const __bf16* __restrict__ Bhi, const __bf16* __restrict__ Blo,
    float* __restrict__ Cf, __bf16* __restrict__ Chi, __bf16* __restrict__ Clo,
    float* __restrict__ Pmax, float* __restrict__ Psum,
    const float* __restrict__ Ffac, float scale) {
  constexpr bool SPLIT = (MODE == MODE_QK || MODE == MODE_S);
  constexpr int  K = (MODE == MODE_PV) ? Sc : Dc;
  constexpr int  N = (MODE == MODE_S) ? Sc : DKc;
  constexpr long aBatch = (MODE == MODE_S) ? (long)Sc * DKc
                        : (MODE == MODE_PV) ? (long)Sc * Sc : 0;
  constexpr long bBatch = (MODE == MODE_S) ? (long)Sc * DKc
                        : (MODE == MODE_PV) ? (long)DKc * Sc : 0;
  constexpr long cBatch = (MODE == MODE_S) ? (long)Sc * Sc
                        : (MODE == MODE_PV) ? (long)Sc * DKc : 0;
  __bf16* sAh = (__bf16*)smem;           // [128][32] (chunk-swizzled)
  __bf16* sBh = sAh + 128 * 32;
  __bf16* sAl = sBh + 128 * 32;          // split only
  __bf16* sBl = sAl + 128 * 32;

  const int b    = blockIdx.z;
  const int wave = threadIdx.x >> 6;
  const int lane = threadIdx.x & 63;
  const int wm   = wave >> 1;            // 0..1
  const int wn   = wave & 1;             // 0..1
  const int m0   = blockIdx.y * 128;
  const int n0   = blockIdx.x * 128;

  const __bf16* Ab  = Ahi + (long)b * aBatch + (long)m0 * K;
  const __bf16* Bb  = Bhi + (long)b * bBatch + (long)n0 * K;
  const __bf16* Abl = SPLIT ? Alo + (long)b * aBatch + (long)m0 * K : nullptr;
  const __bf16* Bbl = SPLIT ? Blo + (long)b * bBatch + (long)n0 * K : nullptr;
  // ffac q-tiles are 256 rows wide (gemm_s2): tile = blockIdx.y>>1.
  const float*  Fb  = (MODE == MODE_PV)
                    ? Ffac + ((long)b * 8 + (blockIdx.y >> 1)) * Sc : nullptr;

  const int sr   = lane >> 2;                       // 0..15
  const int sc_  = lane & 3;                        // 0..3
  const int scol = (sc_ ^ ((sr >> 1) & 3)) * 8;     // swizzled global col

  floatx4 acc[4][4];
  const floatx4 zero = {0.f, 0.f, 0.f, 0.f};
#pragma unroll
  for (int i = 0; i < 4; ++i)
#pragma unroll
    for (int j = 0; j < 4; ++j) acc[i][j] = zero;

  const int frow = lane & 15;
  const int pko = ((lane >> 4) ^ ((frow >> 1) & 3)) * 8;

#pragma unroll 1
  for (int k0 = 0; k0 < K; k0 += 32) {
    if constexpr (MODE == MODE_PV) {
#pragma unroll
      for (int i = 0; i < 2; ++i) {
        const int rb = wave * 32 + i * 16;
        stage16(Bb + (long)(rb + sr) * K + k0 + scol, sBh + rb * 32);
      }
      const int tr = threadIdx.x >> 2;              // 0..63
      const int pc = threadIdx.x & 3;               // physical chunk
#pragma unroll
      for (int h = 0; h < 2; ++h) {
        int r  = h * 64 + tr;
        int lc = pc ^ ((r >> 1) & 3);               // logical chunk
        bf16x8 pv = *(const bf16x8*)(Ab + (long)r * K + k0 + lc * 8);
        const float* fp = Fb + k0 + lc * 8;
        bf16x8 o;
#pragma unroll
        for (int j = 0; j < 8; ++j) o[j] = f2bf(bf2f(pv[j]) * fp[j]);
        *(bf16x8*)(sAh + r * 32 + pc * 8) = o;
      }
    } else {
#pragma unroll
      for (int i = 0; i < 2; ++i) {
        const int rb = wave * 32 + i * 16;          // wave-uniform row base
        const long go = (long)(rb + sr) * K + k0 + scol;
        stage16(Ab + go, sAh + rb * 32);
        stage16(Bb + go, sBh + rb * 32);
        if constexpr (SPLIT) {
          stage16(Abl + go, sAl + rb * 32);
          stage16(Bbl + go, sBl + rb * 32);
        }
      }
    }
    __syncthreads();

    bf16x8 af[4], bfr[4], afl[4], bfl[4];
#pragma unroll
    for (int t = 0; t < 4; ++t) {
      af[t]  = *(const bf16x8*)(sAh + (wm * 64 + t * 16 + frow) * 32 + pko);
      bfr[t] = *(const bf16x8*)(sBh + (wn * 64 + t * 16 + frow) * 32 + pko);
      if constexpr (SPLIT) {
        afl[t] = *(const bf16x8*)(sAl + (wm * 64 + t * 16 + frow) * 32 + pko);
        bfl[t] = *(const bf16x8*)(sBl + (wn * 64 + t * 16 + frow) * 32 + pko);
      }
    }
#pragma unroll
    for (int mt = 0; mt < 4; ++mt)
#pragma unroll
      for (int nt = 0; nt < 4; ++nt) {
        acc[mt][nt] = __builtin_amdgcn_mfma_f32_16x16x32_bf16(af[mt], bfr[nt], acc[mt][nt], 0, 0, 0);
        if constexpr (SPLIT) {
          acc[mt][nt] = __builtin_amdgcn_mfma_f32_16x16x32_bf16(af[mt], bfl[nt], acc[mt][nt], 0, 0, 0);
          acc[mt][nt] = __builtin_amdgcn_mfma_f32_16x16x32_bf16(afl[mt], bfr[nt], acc[mt][nt], 0, 0, 0);
        }
      }
    __syncthreads();
  }

  // Epilogue. D layout: col=lane&15, row=(lane>>4)*4+reg (m89/m91-verified).
  const int crow0 = (lane >> 4) * 4;
  const int ccol  = lane & 15;
  const int tid   = threadIdx.x;

  if constexpr (MODE == MODE_V) {
    __bf16* sT = (__bf16*)smem;          // [128][VSTR]
#pragma unroll
    for (int nt = 0; nt < 4; ++nt) {
      int nl = wn * 64 + nt * 16 + ccol;
#pragma unroll
      for (int mt = 0; mt < 4; ++mt) {
        int ml = wm * 64 + mt * 16 + crow0;
#pragma unroll
        for (int r = 0; r < 4; ++r)
          sT[(long)nl * VSTR + ml + r] = f2bf(acc[mt][nt][r]);
      }
    }
    __syncthreads();
    const int bb   = m0 >> 11;          // tile fully within one batch
    const int seq0 = m0 & (Sc - 1);
    __bf16* dst = Chi + (long)bb * DKc * Sc + seq0;
#pragma unroll
    for (int c = 0; c < 8; ++c) {
      int flat = c * 2048 + tid * 8;    // logical 128x128; 16B per thread
      int row = flat >> 7, col = flat & 127;
      *(bf16x8*)(dst + (long)(n0 + row) * Sc + col) =
          *(const bf16x8*)(sT + (long)row * VSTR + col);
    }
    return;
  }

  if constexpr (MODE == MODE_PV) {
#pragma unroll
    for (int nt = 0; nt < 4; ++nt) {
      int cn = n0 + wn * 64 + nt * 16 + ccol;
#pragma unroll
      for (int mt = 0; mt < 4; ++mt) {
#pragma unroll
        for (int r = 0; r < 4; ++r) {
          int cm_ = m0 + wm * 64 + mt * 16 + crow0 + r;
          Cf[(long)b * cBatch + (long)cm_ * N + cn] = acc[mt][nt][r] * scale;
        }
      }
    }
  }
}

__global__ __launch_bounds__(256) void gemm_v(
    const __bf16* __restrict__ xhi, const __bf16* __restrict__ wvthi,
    __bf16* __restrict__ vt) {
  __shared__ __align__(16) char smem[128 * VSTR * 2];   // 34 KB (epilogue)
  gemm_body<MODE_V>(smem, xhi, nullptr, wvthi, nullptr, nullptr, vt, nullptr,
                    nullptr, nullptr, nullptr, 1.0f);
}

__global__ __launch_bounds__(256) void gemm_pv(
    const __bf16* __restrict__ P, const __bf16* __restrict__ vt,
    float* __restrict__ out, const float* __restrict__ ffac) {
  __shared__ __align__(16) char smem[16384];
  gemm_body<MODE_PV>(smem, P, nullptr, vt, nullptr, out, nullptr, nullptr,
                     nullptr, nullptr, ffac, 1.0f);
}

// ---------------------------------------------------------------------------
// gemm_s2: S = T x^T (split, 3-MFMA) at 256x256/BK=32, 8 waves (2x4), wave
// tile 128x64. 3-phase-per-K-tile pipeline with COUNTED vmcnt (T3/T4).
// Steady waits vmcnt(10/10/11); tail (10,10,8) then (4,2,0). setprio around
// each MFMA cluster (T5). Verified R1: no race, absmax unchanged.
// ---------------------------------------------------------------------------
struct SCtx {
  const __bf16 *pAh, *pAl, *pBh, *pBl;  // per-thread staging src (row+swz col)
  __bf16* lds;
  int stLds;                             // wave*32 rows * 32 elems
  int aoff, boff;                        // frag base offsets (elements)
};

template <int WA, int WB, int WC, bool SAL, bool S2A, bool S2B>
__device__ __forceinline__ void tile_step(const SCtx& c, int t,
                                          floatx4 (&acc)[8][4]) {
  constexpr int K = 1024;
  constexpr int BH = 8192, BL = 16384, AL = 24576;   // region elem offsets
  __bf16* cur = c.lds + (t & 1) * 32768;
  __bf16* oth = c.lds + ((t & 1) ^ 1) * 32768;
  bf16x8 af[8], bfr[4];

  // ---- phase A : acc += Ah * Bh ----
  vmwait<WA>();
  bar_raw();
#pragma unroll
  for (int mt = 0; mt < 8; ++mt)
    af[mt] = *(const bf16x8*)(cur + c.aoff + mt * 512);
#pragma unroll
  for (int nt = 0; nt < 4; ++nt)
    bfr[nt] = *(const bf16x8*)(cur + BH + c.boff + nt * 512);
  if (SAL) {  // stage Al_{t+1} into other buffer (its AL freed last phase)
    const __bf16* s = c.pAl + (t + 1) * 32;
    stage16(s, oth + AL + c.stLds);
    stage16(s + 16 * K, oth + AL + c.stLds + 512);
  }
  bar_raw();
  __builtin_amdgcn_s_setprio(1);
#pragma unroll
  for (int mt = 0; mt < 8; ++mt)
#pragma unroll
    for (int nt = 0; nt < 4; ++nt)
      acc[mt][nt] = __builtin_amdgcn_mfma_f32_16x16x32_bf16(af[mt], bfr[nt], acc[mt][nt], 0, 0, 0);
  __builtin_amdgcn_s_setprio(0);

  // ---- phase B : acc += Ah * Bl ----
  vmwait<WB>();
  bar_raw();
  {
    bf16x8 bfl[4];
#pragma unroll
    for (int nt = 0; nt < 4; ++nt)
      bfl[nt] = *(const bf16x8*)(cur + BL + c.boff + nt * 512);
    if (S2A) {  // Ah_{t+2} x2 + Bh_{t+2} #1 into cur (AH/BH freed in phase A)
      const __bf16* sa = c.pAh + (t + 2) * 32;
      stage16(sa, cur + c.stLds);
      stage16(sa + 16 * K, cur + c.stLds + 512);
      stage16(c.pBh + (t + 2) * 32, cur + BH + c.stLds);
    }
    bar_raw();
    __builtin_amdgcn_s_setprio(1);
#pragma unroll
    for (int mt = 0; mt < 8; ++mt)
#pragma unroll
      for (int nt = 0; nt < 4; ++nt)
        acc[mt][nt] = __builtin_amdgcn_mfma_f32_16x16x32_bf16(af[mt], bfl[nt], acc[mt][nt], 0, 0, 0);
    __builtin_amdgcn_s_setprio(0);
  }

  // ---- phase C : acc += Al * Bh ----
  vmwait<WC>();
  bar_raw();
  {
    bf16x8 afl[8];
#pragma unroll
    for (int mt = 0; mt < 8; ++mt)
      afl[mt] = *(const bf16x8*)(cur + AL + c.aoff + mt * 512);
    if (S2B) {  // Bh_{t+2} #2 + Bl_{t+2} x2 (BL freed in phase B)
      stage16(c.pBh + (t + 2) * 32 + 16 * K, cur + BH + c.stLds + 512);
      const __bf16* sb = c.pBl + (t + 2) * 32;
      stage16(sb, cur + BL + c.stLds);
      stage16(sb + 16 * K, cur + BL + c.stLds + 512);
    }
    bar_raw();
    __builtin_amdgcn_s_setprio(1);
#pragma unroll
    for (int mt = 0; mt < 8; ++mt)
#pragma unroll
      for (int nt = 0; nt < 4; ++nt)
        acc[mt][nt] = __builtin_amdgcn_mfma_f32_16x16x32_bf16(afl[mt], bfr[nt], acc[mt][nt], 0, 0, 0);
    __builtin_amdgcn_s_setprio(0);
  }
}

__global__ __launch_bounds__(512, 2) void gemm_s2(
    const __bf16* __restrict__ thi, const __bf16* __restrict__ tlo,
    const __bf16* __restrict__ xhi, const __bf16* __restrict__ xlo,
    __bf16* __restrict__ P, float* __restrict__ Pmax, float* __restrict__ Psum) {
  __shared__ __align__(16) __bf16 smem[65536];   // 128 KB: 2 x {Ah,Bh,Bl,Al}
  constexpr int K = 1024;
  const int b    = blockIdx.z;
  const int m0   = blockIdx.y * 256;
  const int n0   = blockIdx.x * 256;
  const int wave = threadIdx.x >> 6;
  const int lane = threadIdx.x & 63;
  const int wm   = wave >> 2;            // 0..1
  const int wn   = wave & 3;             // 0..3
  const int sr   = lane >> 2;
  const int scol = ((lane & 3) ^ ((sr >> 1) & 3)) * 8;   // chunk-XOR swizzle
  const int frow = lane & 15;
  const int pko  = ((lane >> 4) ^ ((frow >> 1) & 3)) * 8;

  SCtx c;
  const long batch = (long)Sc * 1024;
  const long ar = (long)(m0 + wave * 32 + sr) * K + scol;
  const long br = (long)(n0 + wave * 32 + sr) * K + scol;
  c.pAh = thi + (long)b * batch + ar;
  c.pAl = tlo + (long)b * batch + ar;
  c.pBh = xhi + (long)b * batch + br;
  c.pBl = xlo + (long)b * batch + br;
  c.lds = smem;
  c.stLds = wave * 1024;
  c.aoff = (wm * 128 + frow) * 32 + pko;
  c.boff = (wn * 64 + frow) * 32 + pko;

  // Prologue: tile0 {Ah,Bh,Bl,Al} + tile1 {Ah,Bh,Bl} (FIFO-order-critical).
  {
    __bf16* b0 = smem;
    __bf16* b1 = smem + 32768;
    stage16(c.pAh, b0 + c.stLds);               stage16(c.pAh + 16 * K, b0 + c.stLds + 512);
    stage16(c.pBh, b0 + 8192 + c.stLds);        stage16(c.pBh + 16 * K, b0 + 8192 + c.stLds + 512);
    stage16(c.pBl, b0 + 16384 + c.stLds);       stage16(c.pBl + 16 * K, b0 + 16384 + c.stLds + 512);
    stage16(c.pAl, b0 + 24576 + c.stLds);       stage16(c.pAl + 16 * K, b0 + 24576 + c.stLds + 512);
    stage16(c.pAh + 32, b1 + c.stLds);          stage16(c.pAh + 32 + 16 * K, b1 + c.stLds + 512);
    stage16(c.pBh + 32, b1 + 8192 + c.stLds);   stage16(c.pBh + 32 + 16 * K, b1 + 8192 + c.stLds + 512);
    stage16(c.pBl + 32, b1 + 16384 + c.stLds);  stage16(c.pBl + 32 + 16 * K, b1 + 16384 + c.stLds + 512);
  }

  floatx4 acc[8][4];
  const floatx4 zero = {0.f, 0.f, 0.f, 0.f};
#pragma unroll
  for (int i = 0; i < 8; ++i)
#pragma unroll
    for (int j = 0; j < 4; ++j) acc[i][j] = zero;

#pragma unroll 1
  for (int t = 0; t < 30; ++t) tile_step<10, 10, 11, true, true, true>(c, t, acc);
  tile_step<10, 10, 8, true, false, false>(c, 30, acc);
  tile_step<4, 2, 0, false, false, false>(c, 31, acc);

  // ---- epilogue: softmax-over-q partials + p = exp(s - M_t) ----
  const int crow0 = (lane >> 4) * 4;
  const int ccol  = lane & 15;
  const int tid   = threadIdx.x;
  constexpr float scale = 0.03125f;
  float* smax = (float*)smem;            // [2][256]
  float* ssum = smax + 512;              // [2][256]

  float cm[4];
#pragma unroll
  for (int nt = 0; nt < 4; ++nt) {
    float mx = -3.0e38f;
#pragma unroll
    for (int mt = 0; mt < 8; ++mt)
#pragma unroll
      for (int r = 0; r < 4; ++r) mx = fmaxf(mx, acc[mt][nt][r] * scale);
    cm[nt] = mx;
  }
#pragma unroll
  for (int off = 16; off <= 32; off <<= 1)
#pragma unroll
    for (int nt = 0; nt < 4; ++nt)
      cm[nt] = fmaxf(cm[nt], __shfl_xor(cm[nt], off, 64));
  __syncthreads();
  if (lane < 16)
#pragma unroll
    for (int nt = 0; nt < 4; ++nt)
      smax[wm * 256 + wn * 64 + nt * 16 + lane] = cm[nt];
  __syncthreads();
  float mfin[4];
#pragma unroll
  for (int nt = 0; nt < 4; ++nt) {
    int cidx = wn * 64 + nt * 16 + ccol;
    mfin[nt] = fmaxf(smax[cidx], smax[256 + cidx]);
  }
  float ps[4];
#pragma unroll
  for (int nt = 0; nt < 4; ++nt) {
    float s = 0.f;
#pragma unroll
    for (int mt = 0; mt < 8; ++mt)
#pragma unroll
      for (int r = 0; r < 4; ++r)
        s += __expf(acc[mt][nt][r] * scale - mfin[nt]);
    ps[nt] = s;
  }
#pragma unroll
  for (int off = 16; off <= 32; off <<= 1)
#pragma unroll
    for (int nt = 0; nt < 4; ++nt) ps[nt] += __shfl_xor(ps[nt], off, 64);
  if (lane < 16)
#pragma unroll
    for (int nt = 0; nt < 4; ++nt)
      ssum[wm * 256 + wn * 64 + nt * 16 + lane] = ps[nt];
  __syncthreads();
  if (tid < 256) {
    long o = ((long)b * 8 + blockIdx.y) * Sc + n0 + tid;
    Pmax[o] = fmaxf(smax[tid], smax[256 + tid]);
    Psum[o] = ssum[tid] + ssum[256 + tid];
  }
  __syncthreads();
  // p -> bf16 via bit4-5 XOR-swizzled LDS round-trip, coalesced 16B stores.
  __bf16* sT = smem;                     // [256][256] = 128 KB
#pragma unroll
  for (int nt = 0; nt < 4; ++nt) {
    int col = wn * 64 + nt * 16 + ccol;
#pragma unroll
    for (int mt = 0; mt < 8; ++mt) {
      int rowb = wm * 128 + mt * 16 + crow0;
#pragma unroll
      for (int r = 0; r < 4; ++r) {
        int row = rowb + r;
        sT[row * 256 + (col ^ (((row >> 2) & 3) << 4))] =
            f2bf(__expf(acc[mt][nt][r] * scale - mfin[nt]));
      }
    }
  }
  __syncthreads();
  __bf16* Pb = P + (long)b * ((long)Sc * Sc);
#pragma unroll
  for (int cc = 0; cc < 16; ++cc) {
    int flat = cc * 4096 + tid * 8;
    int row = flat >> 8, col = flat & 255;
    *(bf16x8*)(Pb + (long)(m0 + row) * Sc + n0 + col) =
        *(const bf16x8*)(sT + row * 256 + (col ^ (((row >> 2) & 3) << 4)));
  }
}

// ---------------------------------------------------------------------------
// gemm_t2: T = x * G (split, 3-MFMA) at 256x128/BK=32, 512 threads, 8 waves
// as 4x2 (wave tile 64x64, acc[4][4]). Same 3-phase counted-vmcnt pipeline as
// gemm_s2. 6 loads/thread/K-tile issued (2,3,1) per phase:
//   A: stage Al(t+1)x2 -> oth.AL      B: Ah(t+2)x2 + Bh(t+2) -> cur
//   C: Bl(t+2) -> cur.BL
// FIFO accounting: steady waits vmcnt(7/8/9); prologue 10 loads
// {Ah0x2,Bh0,Bl0,Al0x2,Ah1x2,Bh1,Bl1}; tails (7,8,6) then (3,2,0).
// Grid (8,32) = 256 blocks = 1/CU; linear->XCD puts each Gt column panel
// (512 KB) in one XCD's L2. LDS 96 KB: 2 x {AH 16K, BH 8K, BL 8K, AL 16K}B.
// ---------------------------------------------------------------------------
struct TCtx {
  const __bf16 *pAh, *pAl, *pBh, *pBl;
  __bf16* lds;
  int stA, stB;                          // wave*1024 (A), wave*512 (B)
  int aoff, boff;
};

template <int WA, int WB, int WC, bool SAL, bool S2AB, bool S2B>
__device__ __forceinline__ void tile_step_t(const TCtx& c, int t,
                                            floatx4 (&acc)[4][4]) {
  constexpr int K = 1024;
  constexpr int BH = 8192, BL = 12288, AL = 16384, BUF = 24576;
  __bf16* cur = c.lds + (t & 1) * BUF;
  __bf16* oth = c.lds + ((t & 1) ^ 1) * BUF;
  bf16x8 af[4], bfr[4];

  // ---- phase A : acc += Ah * Bh ----
  vmwait<WA>();
  bar_raw();
#pragma unroll
  for (int mt = 0; mt < 4; ++mt)
    af[mt] = *(const bf16x8*)(cur + c.aoff + mt * 512);
#pragma unroll
  for (int nt = 0; nt < 4; ++nt)
    bfr[nt] = *(const bf16x8*)(cur + BH + c.boff + nt * 512);
  if (SAL) {
    const __bf16* s = c.pAl + (t + 1) * 32;
    stage16(s, oth + AL + c.stA);
    stage16(s + 16 * K, oth + AL + c.stA + 512);
  }
  bar_raw();
  __builtin_amdgcn_s_setprio(1);
#pragma unroll
  for (int mt = 0; mt < 4; ++mt)
#pragma unroll
    for (int nt = 0; nt < 4; ++nt)
      acc[mt][nt] = __builtin_amdgcn_mfma_f32_16x16x32_bf16(af[mt], bfr[nt], acc[mt][nt], 0, 0, 0);
  __builtin_amdgcn_s_setprio(0);

  // ---- phase B : acc += Ah * Bl ----
  vmwait<WB>();
  bar_raw();
  {
    bf16x8 bfl[4];
#pragma unroll
    for (int nt = 0; nt < 4; ++nt)
      bfl[nt] = *(const bf16x8*)(cur + BL + c.boff + nt * 512);
    if (S2AB) {
      const __bf16* sa = c.pAh + (t + 2) * 32;
      stage16(sa, cur + c.stA);
      stage16(sa + 16 * K, cur + c.stA + 512);
      stage16(c.pBh + (t + 2) * 32, cur + BH + c.stB);
    }
    bar_raw();
    __builtin_amdgcn_s_setprio(1);
#pragma unroll
    for (int mt = 0; mt < 4; ++mt)
#pragma unroll
      for (int nt = 0; nt < 4; ++nt)
        acc[mt][nt] = __builtin_amdgcn_mfma_f32_16x16x32_bf16(af[mt], bfl[nt], acc[mt][nt], 0, 0, 0);
    __builtin_amdgcn_s_setprio(0);
  }

  // ---- phase C : acc += Al * Bh ----
  vmwait<WC>();
  bar_raw();
  {
    bf16x8 afl[4];
#pragma unroll
    for (int mt = 0; mt < 4; ++mt)
      afl[mt] = *(const bf16x8*)(cur + AL + c.aoff + mt * 512);
    if (S2B) stage16(c.pBl + (t + 2) * 32, cur + BL + c.stB);
    bar_raw();
    __builtin_amdgcn_s_setprio(1);
#pragma unroll
    for (int mt = 0; mt < 4; ++mt)
#pragma unroll
      for (int nt = 0; nt < 4; ++nt)
        acc[mt][nt] = __builtin_amdgcn_mfma_f32_16x16x32_bf16(afl[mt], bfr[nt], acc[mt][nt], 0, 0, 0);
    __builtin_amdgcn_s_setprio(0);
  }
}

__global__ __launch_bounds__(512, 2) void gemm_t2(
    const __bf16* __restrict__ xhi, const __bf16* __restrict__ xlo,
    const __bf16* __restrict__ gthi, const __bf16* __restrict__ gtlo,
    __bf16* __restrict__ thi, __bf16* __restrict__ tlo) {
  __shared__ __align__(16) __bf16 smem[49152];   // 96 KB
  constexpr int K = 1024;
  const int m0   = blockIdx.y * 256;
  const int n0   = blockIdx.x * 128;
  const int wave = threadIdx.x >> 6;
  const int lane = threadIdx.x & 63;
  const int wm   = wave >> 1;            // 0..3
  const int wn   = wave & 1;             // 0..1
  const int sr   = lane >> 2;
  const int scol = ((lane & 3) ^ ((sr >> 1) & 3)) * 8;
  const int frow = lane & 15;
  const int pko  = ((lane >> 4) ^ ((frow >> 1) & 3)) * 8;

  TCtx c;
  const long ar = (long)(m0 + wave * 32 + sr) * K + scol;
  const long br = (long)(n0 + wave * 16 + sr) * K + scol;
  c.pAh = xhi + ar;
  c.pAl = xlo + ar;
  c.pBh = gthi + br;
  c.pBl = gtlo + br;
  c.lds = smem;
  c.stA = wave * 1024;
  c.stB = wave * 512;
  c.aoff = (wm * 64 + frow) * 32 + pko;
  c.boff = (wn * 64 + frow) * 32 + pko;

  // Prologue (FIFO-order-critical): Ah0 x2, Bh0, Bl0, Al0 x2, Ah1 x2, Bh1, Bl1.
  {
    __bf16* b0 = smem;
    __bf16* b1 = smem + 24576;
    stage16(c.pAh, b0 + c.stA);          stage16(c.pAh + 16 * K, b0 + c.stA + 512);
    stage16(c.pBh, b0 + 8192 + c.stB);
    stage16(c.pBl, b0 + 12288 + c.stB);
    stage16(c.pAl, b0 + 16384 + c.stA);  stage16(c.pAl + 16 * K, b0 + 16384 + c.stA + 512);
    stage16(c.pAh + 32, b1 + c.stA);     stage16(c.pAh + 32 + 16 * K, b1 + c.stA + 512);
    stage16(c.pBh + 32, b1 + 8192 + c.stB);
    stage16(c.pBl + 32, b1 + 12288 + c.stB);
  }

  floatx4 acc[4][4];
  const floatx4 zero = {0.f, 0.f, 0.f, 0.f};
#pragma unroll
  for (int i = 0; i < 4; ++i)
#pragma unroll
    for (int j = 0; j < 4; ++j) acc[i][j] = zero;

#pragma unroll 1
  for (int t = 0; t < 30; ++t) tile_step_t<7, 8, 9, true, true, true>(c, t, acc);
  tile_step_t<7, 8, 6, true, false, false>(c, 30, acc);
  tile_step_t<3, 2, 0, false, false, false>(c, 31, acc);

  // ---- epilogue: hi/lo split via XOR-swizzled [256][128] LDS round-trip ----
  const int crow0 = (lane >> 4) * 4;
  const int ccol  = lane & 15;
  const int tid   = threadIdx.x;
  __bf16* sT = smem;                     // 64 KB
#pragma unroll 1
  for (int pass = 0; pass < 2; ++pass) {
    __syncthreads();
#pragma unroll
    for (int nt = 0; nt < 4; ++nt) {
      int col = wn * 64 + nt * 16 + ccol;
#pragma unroll
      for (int mt = 0; mt < 4; ++mt) {
        int rowb = wm * 64 + mt * 16 + crow0;
#pragma unroll
        for (int r = 0; r < 4; ++r) {
          int row = rowb + r;
          float v = acc[mt][nt][r];
          __bf16 h = f2bf(v);
          sT[row * 128 + (col ^ (((row >> 2) & 3) << 4))] =
              pass ? f2bf(v - bf2f(h)) : h;
        }
      }
    }
    __syncthreads();
    __bf16* dst = pass ? tlo : thi;
#pragma unroll
    for (int cc = 0; cc < 8; ++cc) {
      int flat = cc * 4096 + tid * 8;
      int row = flat >> 7, col = flat & 127;
      *(bf16x8*)(dst + (long)(m0 + row) * DKc + n0 + col) =
          *(const bf16x8*)(sT + row * 128 + (col ^ (((row >> 2) & 3) << 4)));
    }
  }
}

// ---------------------------------------------------------------------------
// G GEMM, 64x64 tiles (256 blocks). Gt[m][n] = sum_k WK[m,k]WQ[n,k],
// split operands (3 MFMA), hi/lo output.
// ---------------------------------------------------------------------------
__global__ __launch_bounds__(256) void gemm_g64(
    const __bf16* __restrict__ Ahi, const __bf16* __restrict__ Alo,
    const __bf16* __restrict__ Bhi, const __bf16* __restrict__ Blo,
    __bf16* __restrict__ Chi, __bf16* __restrict__ Clo) {
  constexpr int K = Dc, N = DKc;
  __shared__ __align__(16) char smem[16384];
  __bf16* sAh = (__bf16*)smem;           // [64][32]
  __bf16* sBh = sAh + 64 * 32;
  __bf16* sAl = sBh + 64 * 32;
  __bf16* sBl = sAl + 64 * 32;

  const int wave = threadIdx.x >> 6;
  const int lane = threadIdx.x & 63;
  const int wm   = wave >> 1, wn = wave & 1;
  const int m0   = blockIdx.y * 64;
  const int n0   = blockIdx.x * 64;

  const int sr   = lane >> 2;
  const int sc_  = lane & 3;
  const int scol = (sc_ ^ ((sr >> 1) & 3)) * 8;
  const int frow = lane & 15;
  const int pko  = ((lane >> 4) ^ ((frow >> 1) & 3)) * 8;

  floatx4 acc[2][2];
  const floatx4 zero = {0.f, 0.f, 0.f, 0.f};
#pragma unroll
  for (int i = 0; i < 2; ++i)
#pragma unroll
    for (int j = 0; j < 2; ++j) acc[i][j] = zero;

#pragma unroll 1
  for (int k0 = 0; k0 < K; k0 += 32) {
    const int rb = wave * 16;                       // wave stages 16 rows
    const long ga = (long)(m0 + rb + sr) * K + k0 + scol;
    const long gb = (long)(n0 + rb + sr) * K + k0 + scol;
    stage16(Ahi + ga, sAh + rb * 32);
    stage16(Alo + ga, sAl + rb * 32);
    stage16(Bhi + gb, sBh + rb * 32);
    stage16(Blo + gb, sBl + rb * 32);
    __syncthreads();

    bf16x8 af[2], bfr[2], afl[2], bfl[2];
#pragma unroll
    for (int t = 0; t < 2; ++t) {
      af[t]  = *(const bf16x8*)(sAh + (wm * 32 + t * 16 + frow) * 32 + pko);
      bfr[t] = *(const bf16x8*)(sBh + (wn * 32 + t * 16 + frow) * 32 + pko);
      afl[t] = *(const bf16x8*)(sAl + (wm * 32 + t * 16 + frow) * 32 + pko);
      bfl[t] = *(const bf16x8*)(sBl + (wn * 32 + t * 16 + frow) * 32 + pko);
    }
#pragma unroll
    for (int mt = 0; mt < 2; ++mt)
#pragma unroll
      for (int nt = 0; nt < 2; ++nt) {
        acc[mt][nt] = __builtin_amdgcn_mfma_f32_16x16x32_bf16(af[mt], bfr[nt], acc[mt][nt], 0, 0, 0);
        acc[mt][nt] = __builtin_amdgcn_mfma_f32_16x16x32_bf16(af[mt], bfl[nt], acc[mt][nt], 0, 0, 0);
        acc[mt][nt] = __builtin_amdgcn_mfma_f32_16x16x32_bf16(afl[mt], bfr[nt], acc[mt][nt], 0, 0, 0);
      }
    __syncthreads();
  }

  const int crow0 = (lane >> 4) * 4;
  const int ccol  = lane & 15;
  const int tid   = threadIdx.x;
  __bf16* sT = (__bf16*)smem;            // [64][64] = 8KB
#pragma unroll 1
  for (int pass = 0; pass < 2; ++pass) {
    __syncthreads();
#pragma unroll
    for (int nt = 0; nt < 2; ++nt) {
      int col = wn * 32 + nt * 16 + ccol;
#pragma unroll
      for (int mt = 0; mt < 2; ++mt) {
        int row = wm * 32 + mt * 16 + crow0;
#pragma unroll
        for (int r = 0; r < 4; ++r) {
          float v = acc[mt][nt][r];
          __bf16 h = f2bf(v);
          sT[(row + r) * 64 + col] = pass ? f2bf(v - bf2f(h)) : h;
        }
      }
    }
    __syncthreads();
    __bf16* dst = pass ? Clo : Chi;
#pragma unroll
    for (int c = 0; c < 2; ++c) {
      int flat = c * 2048 + tid * 8;
      int row = flat >> 6, col = flat & 63;
      *(bf16x8*)(dst + (long)(m0 + row) * N + n0 + col) = *(const bf16x8*)(sT + flat);
    }
  }
}

// ---------------------------------------------------------------------------
// Fold 8 q-tile partials -> ffac[b][t][k] = exp(M_t - M_k) / Z_k.
// ---------------------------------------------------------------------------
__global__ __launch_bounds__(256) void softmax_reduce(const float* __restrict__ Pmax,
                                                      const float* __restrict__ Psum,
                                                      float* __restrict__ Ffac) {
  int idx = blockIdx.x * 256 + threadIdx.x;   // b*2048 + k
  int b = idx >> 11, k = idx & (Sc - 1);
  const float* pm = Pmax + (long)b * 8 * Sc + k;
  const float* ps = Psum + (long)b * 8 * Sc + k;
  float M = -3.0e38f;
#pragma unroll
  for (int t = 0; t < 8; ++t) M = fmaxf(M, pm[(long)t * Sc]);
  float S = 0.f;
#pragma unroll
  for (int t = 0; t < 8; ++t)
    S += ps[(long)t * Sc] * __expf(pm[(long)t * Sc] - M);
  float inv = 1.0f / S;
  float* fo = Ffac + (long)b * 8 * Sc + k;
#pragma unroll
  for (int t = 0; t < 8; ++t)
    fo[(long)t * Sc] = __expf(pm[(long)t * Sc] - M) * inv;
}

// ---------------------------------------------------------------------------
extern "C" void kernel_launch(void* const* d_in, const int* in_sizes, int n_in,
                              void* d_out, int out_size, void* d_ws, size_t ws_size,
                              hipStream_t stream) {
  const float* x  = (const float*)d_in[0];
  const float* WQ = (const float*)d_in[1];
  const float* WK = (const float*)d_in[2];
  const float* WV = (const float*)d_in[3];
  float* out = (float*)d_out;
  char* ws = (char*)d_ws;
  const long MB = 1024L * 1024L;

  // Workspace layout (peak ~130 MB).
  __bf16* xhi  = (__bf16*)(ws + 0 * MB);     // 16 MB
  __bf16* xlo  = (__bf16*)(ws + 16 * MB);    // 16 MB
  __bf16* wqhi = (__bf16*)(ws + 32 * MB);    // 2 MB each (element-wise split)
  __bf16* wqlo = (__bf16*)(ws + 34 * MB);
  __bf16* wkhi = (__bf16*)(ws + 36 * MB);
  __bf16* wklo = (__bf16*)(ws + 38 * MB);
  __bf16* wvthi= (__bf16*)(ws + 40 * MB);    // transposed, hi only
  __bf16* gthi = (__bf16*)(ws + 44 * MB);    // 2 MB each: Gt = (WQ WK^T)^T
  __bf16* gtlo = (__bf16*)(ws + 46 * MB);
  __bf16* thi  = (__bf16*)(ws + 48 * MB);    // 16 MB each: T = x*G
  __bf16* tlo  = (__bf16*)(ws + 64 * MB);
  __bf16* vt   = (__bf16*)(ws + 80 * MB);    // 16 MB, [B][DK][S]
  __bf16* P    = (__bf16*)(ws + 96 * MB);    // 32 MB, p = exp(s - M_t), bf16
  float*  pmax = (float*)(ws + 128 * MB);    // [B][8][S]
  float*  psum = (float*)(ws + 129 * MB);
  float*  ffac = (float*)(ws + 130 * MB);    // [B][8][S]

  // 1. casts + WV transpose (one dispatch)
  prep<<<41984, 256, 0, stream>>>(x, xhi, xlo, WQ, wqhi, wqlo, WK, wkhi, wklo,
                                  WV, wvthi);

  // 2. Gt[d][a] = G[a][d]: NT(A=WK, B=WQ), 64x64 tiles -> 256 blocks.
  gemm_g64<<<dim3(16, 16), 256, 0, stream>>>(wkhi, wklo, wqhi, wqlo, gthi, gtlo);

  // 3. T = x*G (split) -- 3-phase pipelined 256x128 tiles, 256 blocks.
  gemm_t2<<<dim3(DKc / 128, BSc / 256, 1), 512, 0, stream>>>(
      xhi, xlo, gthi, gtlo, thi, tlo);

  // 4. Vt = (x*WV)^T per batch (plain).
  gemm_v<<<dim3(DKc / 128, BSc / 128, 1), 256, 0, stream>>>(xhi, wvthi, vt);

  // 5. S = T*x^T * scale; emits p (bf16) + per-256-tile column max/expsum.
  gemm_s2<<<dim3(Sc / 256, Sc / 256, Bc), 512, 0, stream>>>(
      thi, tlo, xhi, xlo, P, pmax, psum);

  // 6. partials -> ffac (8 q-tiles)
  softmax_reduce<<<32, 256, 0, stream>>>(pmax, psum, ffac);

  // 7. out = (p .* ffac) @ Vt^T — apply fused into A-staging.
  gemm_pv<<<dim3(DKc / 128, Sc / 128, Bc), 256, 0, stream>>>(P, vt, out, ffac);
}

// Round 3
// 341.540 us; speedup vs baseline: 1.2704x; 1.0512x over previous
//
#include <hip/hip_runtime.h>

// Problem constants (fixed by the reference): B=4, S=2048, D=DK=1024.
constexpr int Bc  = 4;
constexpr int Sc  = 2048;
constexpr int Dc  = 1024;
constexpr int DKc = 1024;
constexpr long BSc = (long)Bc * Sc;      // 8192 flattened rows of x

typedef __attribute__((ext_vector_type(8))) __bf16 bf16x8;
typedef __attribute__((ext_vector_type(4))) float  floatx4;

__device__ inline __bf16 f2bf(float f) {
  unsigned u = __builtin_bit_cast(unsigned, f);
  u = (u + 0x7FFFu + ((u >> 16) & 1u)) >> 16;      // RNE
  unsigned short s = (unsigned short)u;
  return __builtin_bit_cast(__bf16, s);
}
__device__ inline float bf2f(__bf16 h) {
  unsigned u = ((unsigned)__builtin_bit_cast(unsigned short, h)) << 16;
  return __builtin_bit_cast(float, u);
}

// async global->LDS, 16B per lane. lds base must be wave-uniform; HW scatters
// lane i's 16B to ldsbase + i*16.
__device__ inline void stage16(const __bf16* g, __bf16* l) {
  __builtin_amdgcn_global_load_lds(
      (const __attribute__((address_space(1))) unsigned int*)g,
      (__attribute__((address_space(3))) unsigned int*)l, 16, 0, 0);
}

__device__ __forceinline__ void bar_raw() {
  asm volatile("" ::: "memory");
  __builtin_amdgcn_s_barrier();
  asm volatile("" ::: "memory");
}
template <int N>
__device__ __forceinline__ void vmwait() {
  asm volatile("s_waitcnt vmcnt(%0)" :: "n"(N));
  __builtin_amdgcn_sched_barrier(0);
}

// ---------------------------------------------------------------------------
// prep: fp32->bf16 hi/lo splits for x (32768 blks), WQ (4096), WK (4096),
// plus WV transpose (hi only; 1024 blks). One dispatch (round-7).
// ---------------------------------------------------------------------------
__global__ __launch_bounds__(256) void prep(
    const float* __restrict__ x,  __bf16* __restrict__ xhi, __bf16* __restrict__ xlo,
    const float* __restrict__ wq, __bf16* __restrict__ qhi, __bf16* __restrict__ qlo,
    const float* __restrict__ wk, __bf16* __restrict__ khi, __bf16* __restrict__ klo,
    const float* __restrict__ wv, __bf16* __restrict__ vthi) {
  __shared__ float tile[32][33];
  long blk = blockIdx.x;
  if (blk >= 40960) {                 // WV transpose: Wt[dk][d] = W[d][dk]
    int t   = (int)(blk - 40960);
    int bx  = t & 31, by = t >> 5;
    int thx = threadIdx.x & 31, thy = threadIdx.x >> 5;   // 32 x 8
    int xI  = bx * 32 + thx, yI = by * 32 + thy;
#pragma unroll
    for (int j = 0; j < 32; j += 8)
      tile[thy + j][thx] = wv[(long)(yI + j) * DKc + xI];
    __syncthreads();
    int xO = by * 32 + thx, yO = bx * 32 + thy;
#pragma unroll
    for (int j = 0; j < 32; j += 8)
      vthi[(long)(yO + j) * Dc + xO] = f2bf(tile[thx][thy + j]);
    return;
  }
  const float* in; __bf16 *hi, *lo; long base;
  if (blk < 32768)      { in = x;  hi = xhi; lo = xlo; base = blk * 256; }
  else if (blk < 36864) { in = wq; hi = qhi; lo = qlo; base = (blk - 32768) * 256; }
  else                  { in = wk; hi = khi; lo = klo; base = (blk - 36864) * 256; }
  long i = base + threadIdx.x;
  float f = in[i];
  __bf16 h = f2bf(f);
  hi[i] = h;
  lo[i] = f2bf(f - bf2f(h));
}

// ---------------------------------------------------------------------------
// m97-structure NT MFMA GEMM body (kept for the V mode only).
// ---------------------------------------------------------------------------
enum { MODE_V = 1 };
constexpr int VSTR = 136;   // padded stride for the V transpose epilogue

template <int MODE>
__device__ __forceinline__ void gemm_body(
    char* smem,
    const __bf16* __restrict__ Ahi,
    const __bf16* __restrict__ Bhi,
    __bf16* __restrict__ Chi) {
  constexpr int  K = Dc;
  __bf16* sAh = (__bf16*)smem;           // [128][32] (chunk-swizzled)
  __bf16* sBh = sAh + 128 * 32;

  const int wave = threadIdx.x >> 6;
  const int lane = threadIdx.x & 63;
  const int wm   = wave >> 1;            // 0..1
  const int wn   = wave & 1;             // 0..1
  const int m0   = blockIdx.y * 128;
  const int n0   = blockIdx.x * 128;

  const __bf16* Ab  = Ahi + (long)m0 * K;
  const __bf16* Bb  = Bhi + (long)n0 * K;

  const int sr   = lane >> 2;                       // 0..15
  const int sc_  = lane & 3;                        // 0..3
  const int scol = (sc_ ^ ((sr >> 1) & 3)) * 8;     // swizzled global col

  floatx4 acc[4][4];
  const floatx4 zero = {0.f, 0.f, 0.f, 0.f};
#pragma unroll
  for (int i = 0; i < 4; ++i)
#pragma unroll
    for (int j = 0; j < 4; ++j) acc[i][j] = zero;

  const int frow = lane & 15;
  const int pko = ((lane >> 4) ^ ((frow >> 1) & 3)) * 8;

#pragma unroll 1
  for (int k0 = 0; k0 < K; k0 += 32) {
#pragma unroll
    for (int i = 0; i < 2; ++i) {
      const int rb = wave * 32 + i * 16;          // wave-uniform row base
      const long go = (long)(rb + sr) * K + k0 + scol;
      stage16(Ab + go, sAh + rb * 32);
      stage16(Bb + go, sBh + rb * 32);
    }
    __syncthreads();

    bf16x8 af[4], bfr[4];
#pragma unroll
    for (int t = 0; t < 4; ++t) {
      af[t]  = *(const bf16x8*)(sAh + (wm * 64 + t * 16 + frow) * 32 + pko);
      bfr[t] = *(const bf16x8*)(sBh + (wn * 64 + t * 16 + frow) * 32 + pko);
    }
#pragma unroll
    for (int mt = 0; mt < 4; ++mt)
#pragma unroll
      for (int nt = 0; nt < 4; ++nt)
        acc[mt][nt] = __builtin_amdgcn_mfma_f32_16x16x32_bf16(af[mt], bfr[nt], acc[mt][nt], 0, 0, 0);
    __syncthreads();
  }

  // Epilogue. D layout: col=lane&15, row=(lane>>4)*4+reg (m89/m91-verified).
  const int crow0 = (lane >> 4) * 4;
  const int ccol  = lane & 15;
  const int tid   = threadIdx.x;

  // Transpose via LDS, padded stride VSTR=136.
  __bf16* sT = (__bf16*)smem;          // [128][VSTR]
#pragma unroll
  for (int nt = 0; nt < 4; ++nt) {
    int nl = wn * 64 + nt * 16 + ccol;
#pragma unroll
    for (int mt = 0; mt < 4; ++mt) {
      int ml = wm * 64 + mt * 16 + crow0;
#pragma unroll
      for (int r = 0; r < 4; ++r)
        sT[(long)nl * VSTR + ml + r] = f2bf(acc[mt][nt][r]);
    }
  }
  __syncthreads();
  const int bb   = m0 >> 11;          // tile fully within one batch
  const int seq0 = m0 & (Sc - 1);
  __bf16* dst = Chi + (long)bb * DKc * Sc + seq0;
#pragma unroll
  for (int c = 0; c < 8; ++c) {
    int flat = c * 2048 + tid * 8;    // logical 128x128; 16B per thread
    int row = flat >> 7, col = flat & 127;
    *(bf16x8*)(dst + (long)(n0 + row) * Sc + col) =
        *(const bf16x8*)(sT + (long)row * VSTR + col);
  }
}

__global__ __launch_bounds__(256) void gemm_v(
    const __bf16* __restrict__ xhi, const __bf16* __restrict__ wvthi,
    __bf16* __restrict__ vt) {
  __shared__ __align__(16) char smem[128 * VSTR * 2];   // 34 KB (epilogue)
  gemm_body<MODE_V>(smem, xhi, wvthi, vt);
}

// ---------------------------------------------------------------------------
// gemm_s2: S = T x^T (split, 3-MFMA) at 256x256/BK=32, 8 waves (2x4), wave
// tile 128x64. 3-phase-per-K-tile pipeline with COUNTED vmcnt (T3/T4).
// Steady waits vmcnt(10/10/11); tail (10,10,8) then (4,2,0). setprio around
// each MFMA cluster (T5). Verified R1: no race, absmax unchanged.
// ---------------------------------------------------------------------------
struct SCtx {
  const __bf16 *pAh, *pAl, *pBh, *pBl;  // per-thread staging src (row+swz col)
  __bf16* lds;
  int stLds;                             // wave*32 rows * 32 elems
  int aoff, boff;                        // frag base offsets (elements)
};

template <int WA, int WB, int WC, bool SAL, bool S2A, bool S2B>
__device__ __forceinline__ void tile_step(const SCtx& c, int t,
                                          floatx4 (&acc)[8][4]) {
  constexpr int K = 1024;
  constexpr int BH = 8192, BL = 16384, AL = 24576;   // region elem offsets
  __bf16* cur = c.lds + (t & 1) * 32768;
  __bf16* oth = c.lds + ((t & 1) ^ 1) * 32768;
  bf16x8 af[8], bfr[4];

  // ---- phase A : acc += Ah * Bh ----
  vmwait<WA>();
  bar_raw();
#pragma unroll
  for (int mt = 0; mt < 8; ++mt)
    af[mt] = *(const bf16x8*)(cur + c.aoff + mt * 512);
#pragma unroll
  for (int nt = 0; nt < 4; ++nt)
    bfr[nt] = *(const bf16x8*)(cur + BH + c.boff + nt * 512);
  if (SAL) {  // stage Al_{t+1} into other buffer (its AL freed last phase)
    const __bf16* s = c.pAl + (t + 1) * 32;
    stage16(s, oth + AL + c.stLds);
    stage16(s + 16 * K, oth + AL + c.stLds + 512);
  }
  bar_raw();
  __builtin_amdgcn_s_setprio(1);
#pragma unroll
  for (int mt = 0; mt < 8; ++mt)
#pragma unroll
    for (int nt = 0; nt < 4; ++nt)
      acc[mt][nt] = __builtin_amdgcn_mfma_f32_16x16x32_bf16(af[mt], bfr[nt], acc[mt][nt], 0, 0, 0);
  __builtin_amdgcn_s_setprio(0);

  // ---- phase B : acc += Ah * Bl ----
  vmwait<WB>();
  bar_raw();
  {
    bf16x8 bfl[4];
#pragma unroll
    for (int nt = 0; nt < 4; ++nt)
      bfl[nt] = *(const bf16x8*)(cur + BL + c.boff + nt * 512);
    if (S2A) {  // Ah_{t+2} x2 + Bh_{t+2} #1 into cur (AH/BH freed in phase A)
      const __bf16* sa = c.pAh + (t + 2) * 32;
      stage16(sa, cur + c.stLds);
      stage16(sa + 16 * K, cur + c.stLds + 512);
      stage16(c.pBh + (t + 2) * 32, cur + BH + c.stLds);
    }
    bar_raw();
    __builtin_amdgcn_s_setprio(1);
#pragma unroll
    for (int mt = 0; mt < 8; ++mt)
#pragma unroll
      for (int nt = 0; nt < 4; ++nt)
        acc[mt][nt] = __builtin_amdgcn_mfma_f32_16x16x32_bf16(af[mt], bfl[nt], acc[mt][nt], 0, 0, 0);
    __builtin_amdgcn_s_setprio(0);
  }

  // ---- phase C : acc += Al * Bh ----
  vmwait<WC>();
  bar_raw();
  {
    bf16x8 afl[8];
#pragma unroll
    for (int mt = 0; mt < 8; ++mt)
      afl[mt] = *(const bf16x8*)(cur + AL + c.aoff + mt * 512);
    if (S2B) {  // Bh_{t+2} #2 + Bl_{t+2} x2 (BL freed in phase B)
      stage16(c.pBh + (t + 2) * 32 + 16 * K, cur + BH + c.stLds + 512);
      const __bf16* sb = c.pBl + (t + 2) * 32;
      stage16(sb, cur + BL + c.stLds);
      stage16(sb + 16 * K, cur + BL + c.stLds + 512);
    }
    bar_raw();
    __builtin_amdgcn_s_setprio(1);
#pragma unroll
    for (int mt = 0; mt < 8; ++mt)
#pragma unroll
      for (int nt = 0; nt < 4; ++nt)
        acc[mt][nt] = __builtin_amdgcn_mfma_f32_16x16x32_bf16(afl[mt], bfr[nt], acc[mt][nt], 0, 0, 0);
    __builtin_amdgcn_s_setprio(0);
  }
}

__global__ __launch_bounds__(512, 2) void gemm_s2(
    const __bf16* __restrict__ thi, const __bf16* __restrict__ tlo,
    const __bf16* __restrict__ xhi, const __bf16* __restrict__ xlo,
    __bf16* __restrict__ P, float* __restrict__ Pmax, float* __restrict__ Psum) {
  __shared__ __align__(16) __bf16 smem[65536];   // 128 KB: 2 x {Ah,Bh,Bl,Al}
  constexpr int K = 1024;
  const int b    = blockIdx.z;
  const int m0   = blockIdx.y * 256;
  const int n0   = blockIdx.x * 256;
  const int wave = threadIdx.x >> 6;
  const int lane = threadIdx.x & 63;
  const int wm   = wave >> 2;            // 0..1
  const int wn   = wave & 3;             // 0..3
  const int sr   = lane >> 2;
  const int scol = ((lane & 3) ^ ((sr >> 1) & 3)) * 8;   // chunk-XOR swizzle
  const int frow = lane & 15;
  const int pko  = ((lane >> 4) ^ ((frow >> 1) & 3)) * 8;

  SCtx c;
  const long batch = (long)Sc * 1024;
  const long ar = (long)(m0 + wave * 32 + sr) * K + scol;
  const long br = (long)(n0 + wave * 32 + sr) * K + scol;
  c.pAh = thi + (long)b * batch + ar;
  c.pAl = tlo + (long)b * batch + ar;
  c.pBh = xhi + (long)b * batch + br;
  c.pBl = xlo + (long)b * batch + br;
  c.lds = smem;
  c.stLds = wave * 1024;
  c.aoff = (wm * 128 + frow) * 32 + pko;
  c.boff = (wn * 64 + frow) * 32 + pko;

  // Prologue: tile0 {Ah,Bh,Bl,Al} + tile1 {Ah,Bh,Bl} (FIFO-order-critical).
  {
    __bf16* b0 = smem;
    __bf16* b1 = smem + 32768;
    stage16(c.pAh, b0 + c.stLds);               stage16(c.pAh + 16 * K, b0 + c.stLds + 512);
    stage16(c.pBh, b0 + 8192 + c.stLds);        stage16(c.pBh + 16 * K, b0 + 8192 + c.stLds + 512);
    stage16(c.pBl, b0 + 16384 + c.stLds);       stage16(c.pBl + 16 * K, b0 + 16384 + c.stLds + 512);
    stage16(c.pAl, b0 + 24576 + c.stLds);       stage16(c.pAl + 16 * K, b0 + 24576 + c.stLds + 512);
    stage16(c.pAh + 32, b1 + c.stLds);          stage16(c.pAh + 32 + 16 * K, b1 + c.stLds + 512);
    stage16(c.pBh + 32, b1 + 8192 + c.stLds);   stage16(c.pBh + 32 + 16 * K, b1 + 8192 + c.stLds + 512);
    stage16(c.pBl + 32, b1 + 16384 + c.stLds);  stage16(c.pBl + 32 + 16 * K, b1 + 16384 + c.stLds + 512);
  }

  floatx4 acc[8][4];
  const floatx4 zero = {0.f, 0.f, 0.f, 0.f};
#pragma unroll
  for (int i = 0; i < 8; ++i)
#pragma unroll
    for (int j = 0; j < 4; ++j) acc[i][j] = zero;

#pragma unroll 1
  for (int t = 0; t < 30; ++t) tile_step<10, 10, 11, true, true, true>(c, t, acc);
  tile_step<10, 10, 8, true, false, false>(c, 30, acc);
  tile_step<4, 2, 0, false, false, false>(c, 31, acc);

  // ---- epilogue: softmax-over-q partials + p = exp(s - M_t) ----
  const int crow0 = (lane >> 4) * 4;
  const int ccol  = lane & 15;
  const int tid   = threadIdx.x;
  constexpr float scale = 0.03125f;
  float* smax = (float*)smem;            // [2][256]
  float* ssum = smax + 512;              // [2][256]

  float cm[4];
#pragma unroll
  for (int nt = 0; nt < 4; ++nt) {
    float mx = -3.0e38f;
#pragma unroll
    for (int mt = 0; mt < 8; ++mt)
#pragma unroll
      for (int r = 0; r < 4; ++r) mx = fmaxf(mx, acc[mt][nt][r] * scale);
    cm[nt] = mx;
  }
#pragma unroll
  for (int off = 16; off <= 32; off <<= 1)
#pragma unroll
    for (int nt = 0; nt < 4; ++nt)
      cm[nt] = fmaxf(cm[nt], __shfl_xor(cm[nt], off, 64));
  __syncthreads();
  if (lane < 16)
#pragma unroll
    for (int nt = 0; nt < 4; ++nt)
      smax[wm * 256 + wn * 64 + nt * 16 + lane] = cm[nt];
  __syncthreads();
  float mfin[4];
#pragma unroll
  for (int nt = 0; nt < 4; ++nt) {
    int cidx = wn * 64 + nt * 16 + ccol;
    mfin[nt] = fmaxf(smax[cidx], smax[256 + cidx]);
  }
  float ps[4];
#pragma unroll
  for (int nt = 0; nt < 4; ++nt) {
    float s = 0.f;
#pragma unroll
    for (int mt = 0; mt < 8; ++mt)
#pragma unroll
      for (int r = 0; r < 4; ++r)
        s += __expf(acc[mt][nt][r] * scale - mfin[nt]);
    ps[nt] = s;
  }
#pragma unroll
  for (int off = 16; off <= 32; off <<= 1)
#pragma unroll
    for (int nt = 0; nt < 4; ++nt) ps[nt] += __shfl_xor(ps[nt], off, 64);
  if (lane < 16)
#pragma unroll
    for (int nt = 0; nt < 4; ++nt)
      ssum[wm * 256 + wn * 64 + nt * 16 + lane] = ps[nt];
  __syncthreads();
  if (tid < 256) {
    long o = ((long)b * 8 + blockIdx.y) * Sc + n0 + tid;
    Pmax[o] = fmaxf(smax[tid], smax[256 + tid]);
    Psum[o] = ssum[tid] + ssum[256 + tid];
  }
  __syncthreads();
  // p -> bf16 via bit4-5 XOR-swizzled LDS round-trip, coalesced 16B stores.
  __bf16* sT = smem;                     // [256][256] = 128 KB
#pragma unroll
  for (int nt = 0; nt < 4; ++nt) {
    int col = wn * 64 + nt * 16 + ccol;
#pragma unroll
    for (int mt = 0; mt < 8; ++mt) {
      int rowb = wm * 128 + mt * 16 + crow0;
#pragma unroll
      for (int r = 0; r < 4; ++r) {
        int row = rowb + r;
        sT[row * 256 + (col ^ (((row >> 2) & 3) << 4))] =
            f2bf(__expf(acc[mt][nt][r] * scale - mfin[nt]));
      }
    }
  }
  __syncthreads();
  __bf16* Pb = P + (long)b * ((long)Sc * Sc);
#pragma unroll
  for (int cc = 0; cc < 16; ++cc) {
    int flat = cc * 4096 + tid * 8;
    int row = flat >> 8, col = flat & 255;
    *(bf16x8*)(Pb + (long)(m0 + row) * Sc + n0 + col) =
        *(const bf16x8*)(sT + row * 256 + (col ^ (((row >> 2) & 3) << 4)));
  }
}

// ---------------------------------------------------------------------------
// gemm_t2: T = x * G (split, 3-MFMA) at 256x128/BK=32, 512 threads, 8 waves
// as 4x2 (wave tile 64x64, acc[4][4]). 3-phase counted-vmcnt pipeline.
// Steady waits vmcnt(7/8/9); tails (7,8,6) then (3,2,0). Verified R2.
// ---------------------------------------------------------------------------
struct TCtx {
  const __bf16 *pAh, *pAl, *pBh, *pBl;
  __bf16* lds;
  int stA, stB;                          // wave*1024 (A), wave*512 (B)
  int aoff, boff;
};

template <int WA, int WB, int WC, bool SAL, bool S2AB, bool S2B>
__device__ __forceinline__ void tile_step_t(const TCtx& c, int t,
                                            floatx4 (&acc)[4][4]) {
  constexpr int K = 1024;
  constexpr int BH = 8192, BL = 12288, AL = 16384, BUF = 24576;
  __bf16* cur = c.lds + (t & 1) * BUF;
  __bf16* oth = c.lds + ((t & 1) ^ 1) * BUF;
  bf16x8 af[4], bfr[4];

  // ---- phase A : acc += Ah * Bh ----
  vmwait<WA>();
  bar_raw();
#pragma unroll
  for (int mt = 0; mt < 4; ++mt)
    af[mt] = *(const bf16x8*)(cur + c.aoff + mt * 512);
#pragma unroll
  for (int nt = 0; nt < 4; ++nt)
    bfr[nt] = *(const bf16x8*)(cur + BH + c.boff + nt * 512);
  if (SAL) {
    const __bf16* s = c.pAl + (t + 1) * 32;
    stage16(s, oth + AL + c.stA);
    stage16(s + 16 * K, oth + AL + c.stA + 512);
  }
  bar_raw();
  __builtin_amdgcn_s_setprio(1);
#pragma unroll
  for (int mt = 0; mt < 4; ++mt)
#pragma unroll
    for (int nt = 0; nt < 4; ++nt)
      acc[mt][nt] = __builtin_amdgcn_mfma_f32_16x16x32_bf16(af[mt], bfr[nt], acc[mt][nt], 0, 0, 0);
  __builtin_amdgcn_s_setprio(0);

  // ---- phase B : acc += Ah * Bl ----
  vmwait<WB>();
  bar_raw();
  {
    bf16x8 bfl[4];
#pragma unroll
    for (int nt = 0; nt < 4; ++nt)
      bfl[nt] = *(const bf16x8*)(cur + BL + c.boff + nt * 512);
    if (S2AB) {
      const __bf16* sa = c.pAh + (t + 2) * 32;
      stage16(sa, cur + c.stA);
      stage16(sa + 16 * K, cur + c.stA + 512);
      stage16(c.pBh + (t + 2) * 32, cur + BH + c.stB);
    }
    bar_raw();
    __builtin_amdgcn_s_setprio(1);
#pragma unroll
    for (int mt = 0; mt < 4; ++mt)
#pragma unroll
      for (int nt = 0; nt < 4; ++nt)
        acc[mt][nt] = __builtin_amdgcn_mfma_f32_16x16x32_bf16(af[mt], bfl[nt], acc[mt][nt], 0, 0, 0);
    __builtin_amdgcn_s_setprio(0);
  }

  // ---- phase C : acc += Al * Bh ----
  vmwait<WC>();
  bar_raw();
  {
    bf16x8 afl[4];
#pragma unroll
    for (int mt = 0; mt < 4; ++mt)
      afl[mt] = *(const bf16x8*)(cur + AL + c.aoff + mt * 512);
    if (S2B) stage16(c.pBl + (t + 2) * 32, cur + BL + c.stB);
    bar_raw();
    __builtin_amdgcn_s_setprio(1);
#pragma unroll
    for (int mt = 0; mt < 4; ++mt)
#pragma unroll
      for (int nt = 0; nt < 4; ++nt)
        acc[mt][nt] = __builtin_amdgcn_mfma_f32_16x16x32_bf16(afl[mt], bfr[nt], acc[mt][nt], 0, 0, 0);
    __builtin_amdgcn_s_setprio(0);
  }
}

__global__ __launch_bounds__(512, 2) void gemm_t2(
    const __bf16* __restrict__ xhi, const __bf16* __restrict__ xlo,
    const __bf16* __restrict__ gthi, const __bf16* __restrict__ gtlo,
    __bf16* __restrict__ thi, __bf16* __restrict__ tlo) {
  __shared__ __align__(16) __bf16 smem[49152];   // 96 KB
  constexpr int K = 1024;
  const int m0   = blockIdx.y * 256;
  const int n0   = blockIdx.x * 128;
  const int wave = threadIdx.x >> 6;
  const int lane = threadIdx.x & 63;
  const int wm   = wave >> 1;            // 0..3
  const int wn   = wave & 1;             // 0..1
  const int sr   = lane >> 2;
  const int scol = ((lane & 3) ^ ((sr >> 1) & 3)) * 8;
  const int frow = lane & 15;
  const int pko  = ((lane >> 4) ^ ((frow >> 1) & 3)) * 8;

  TCtx c;
  const long ar = (long)(m0 + wave * 32 + sr) * K + scol;
  const long br = (long)(n0 + wave * 16 + sr) * K + scol;
  c.pAh = xhi + ar;
  c.pAl = xlo + ar;
  c.pBh = gthi + br;
  c.pBl = gtlo + br;
  c.lds = smem;
  c.stA = wave * 1024;
  c.stB = wave * 512;
  c.aoff = (wm * 64 + frow) * 32 + pko;
  c.boff = (wn * 64 + frow) * 32 + pko;

  // Prologue (FIFO-order-critical): Ah0 x2, Bh0, Bl0, Al0 x2, Ah1 x2, Bh1, Bl1.
  {
    __bf16* b0 = smem;
    __bf16* b1 = smem + 24576;
    stage16(c.pAh, b0 + c.stA);          stage16(c.pAh + 16 * K, b0 + c.stA + 512);
    stage16(c.pBh, b0 + 8192 + c.stB);
    stage16(c.pBl, b0 + 12288 + c.stB);
    stage16(c.pAl, b0 + 16384 + c.stA);  stage16(c.pAl + 16 * K, b0 + 16384 + c.stA + 512);
    stage16(c.pAh + 32, b1 + c.stA);     stage16(c.pAh + 32 + 16 * K, b1 + c.stA + 512);
    stage16(c.pBh + 32, b1 + 8192 + c.stB);
    stage16(c.pBl + 32, b1 + 12288 + c.stB);
  }

  floatx4 acc[4][4];
  const floatx4 zero = {0.f, 0.f, 0.f, 0.f};
#pragma unroll
  for (int i = 0; i < 4; ++i)
#pragma unroll
    for (int j = 0; j < 4; ++j) acc[i][j] = zero;

#pragma unroll 1
  for (int t = 0; t < 30; ++t) tile_step_t<7, 8, 9, true, true, true>(c, t, acc);
  tile_step_t<7, 8, 6, true, false, false>(c, 30, acc);
  tile_step_t<3, 2, 0, false, false, false>(c, 31, acc);

  // ---- epilogue: hi/lo split via XOR-swizzled [256][128] LDS round-trip ----
  const int crow0 = (lane >> 4) * 4;
  const int ccol  = lane & 15;
  const int tid   = threadIdx.x;
  __bf16* sT = smem;                     // 64 KB
#pragma unroll 1
  for (int pass = 0; pass < 2; ++pass) {
    __syncthreads();
#pragma unroll
    for (int nt = 0; nt < 4; ++nt) {
      int col = wn * 64 + nt * 16 + ccol;
#pragma unroll
      for (int mt = 0; mt < 4; ++mt) {
        int rowb = wm * 64 + mt * 16 + crow0;
#pragma unroll
        for (int r = 0; r < 4; ++r) {
          int row = rowb + r;
          float v = acc[mt][nt][r];
          __bf16 h = f2bf(v);
          sT[row * 128 + (col ^ (((row >> 2) & 3) << 4))] =
              pass ? f2bf(v - bf2f(h)) : h;
        }
      }
    }
    __syncthreads();
    __bf16* dst = pass ? tlo : thi;
#pragma unroll
    for (int cc = 0; cc < 8; ++cc) {
      int flat = cc * 4096 + tid * 8;
      int row = flat >> 7, col = flat & 127;
      *(bf16x8*)(dst + (long)(m0 + row) * DKc + n0 + col) =
          *(const bf16x8*)(sT + row * 128 + (col ^ (((row >> 2) & 3) << 4)));
    }
  }
}

// ---------------------------------------------------------------------------
// scale_p: P <- P .* ffac[b][t(q)][k]  (elementwise, memory-bound).
// Exactly the multiply the old gemm_pv did in its A-staging, moved to a
// pass where VALU is free. 8192 blocks x 256 threads x 8 elems = 16.78M.
// ---------------------------------------------------------------------------
__global__ __launch_bounds__(256) void scale_p(__bf16* __restrict__ P,
                                               const float* __restrict__ ffac) {
  long i8 = (long)blockIdx.x * 256 + threadIdx.x;
  long base = i8 * 8;
  int k = (int)(base & (Sc - 1));
  int q = (int)((base >> 11) & (Sc - 1));
  int b = (int)(base >> 22);
  int t = q >> 8;                         // 256-row q-tiles
  const float* f = ffac + (((long)b * 8 + t) << 11) + k;
  float4 f0 = *(const float4*)f;
  float4 f1 = *(const float4*)(f + 4);
  bf16x8 p = *(const bf16x8*)(P + base);
  bf16x8 o;
  o[0] = f2bf(bf2f(p[0]) * f0.x);
  o[1] = f2bf(bf2f(p[1]) * f0.y);
  o[2] = f2bf(bf2f(p[2]) * f0.z);
  o[3] = f2bf(bf2f(p[3]) * f0.w);
  o[4] = f2bf(bf2f(p[4]) * f1.x);
  o[5] = f2bf(bf2f(p[5]) * f1.y);
  o[6] = f2bf(bf2f(p[6]) * f1.z);
  o[7] = f2bf(bf2f(p[7]) * f1.w);
  *(bf16x8*)(P + base) = o;
}

// ---------------------------------------------------------------------------
// gemm_pv2: out = attn @ Vt^T, plain NT GEMM (A = scaled P, B = Vt), 256x128
// tile, BK=64 split in 2 k-half phases, 512 threads, 8 waves 4x2 (wave tile
// 64x64). 3 LDS buffers (144 KB), counted vmcnt, t+2 prefetch:
// 3 loads/phase {A x2, B x1}; steady vmcnt(9); tails (9,6) then (3,0).
// Grid (x=q 8, y=dk 8, z=b 4): blocks sharing the P-panel sit on ONE XCD
// (4 x 1 MB panels/XCD -> L2-resident); Vt refetch stays L3-resident.
// Buffer regions (elems): A0=0, A1=8192, B0=16384, B1=20480; buffer=24576.
// ---------------------------------------------------------------------------
struct PCtx {
  const __bf16 *pA, *pB;
  int stA, stB;                          // wave*1024 (A), wave*512 (B)
  int aoff, boff;
};

template <int WA, int WB, bool STG>
__device__ __forceinline__ void tile_step_pv(const PCtx& c, int t,
                                             __bf16* cur, __bf16* dst,
                                             floatx4 (&acc)[4][4]) {
  constexpr int K = 2048;
  // ---- phase A : k-half 0 ----
  vmwait<WA>();
  bar_raw();
  {
    bf16x8 af[4], bfr[4];
#pragma unroll
    for (int mt = 0; mt < 4; ++mt)
      af[mt] = *(const bf16x8*)(cur + c.aoff + mt * 512);
#pragma unroll
    for (int nt = 0; nt < 4; ++nt)
      bfr[nt] = *(const bf16x8*)(cur + 16384 + c.boff + nt * 512);
    if (STG) {
      const __bf16* a = c.pA + (t + 2) * 64;
      stage16(a, dst + c.stA);
      stage16(a + 16 * K, dst + c.stA + 512);
      stage16(c.pB + (t + 2) * 64, dst + 16384 + c.stB);
    }
    bar_raw();
    __builtin_amdgcn_s_setprio(1);
#pragma unroll
    for (int mt = 0; mt < 4; ++mt)
#pragma unroll
      for (int nt = 0; nt < 4; ++nt)
        acc[mt][nt] = __builtin_amdgcn_mfma_f32_16x16x32_bf16(af[mt], bfr[nt], acc[mt][nt], 0, 0, 0);
    __builtin_amdgcn_s_setprio(0);
  }
  // ---- phase B : k-half 1 ----
  vmwait<WB>();
  bar_raw();
  {
    bf16x8 af[4], bfr[4];
#pragma unroll
    for (int mt = 0; mt < 4; ++mt)
      af[mt] = *(const bf16x8*)(cur + 8192 + c.aoff + mt * 512);
#pragma unroll
    for (int nt = 0; nt < 4; ++nt)
      bfr[nt] = *(const bf16x8*)(cur + 20480 + c.boff + nt * 512);
    if (STG) {
      const __bf16* a = c.pA + (t + 2) * 64 + 32;
      stage16(a, dst + 8192 + c.stA);
      stage16(a + 16 * K, dst + 8192 + c.stA + 512);
      stage16(c.pB + (t + 2) * 64 + 32, dst + 20480 + c.stB);
    }
    bar_raw();
    __builtin_amdgcn_s_setprio(1);
#pragma unroll
    for (int mt = 0; mt < 4; ++mt)
#pragma unroll
      for (int nt = 0; nt < 4; ++nt)
        acc[mt][nt] = __builtin_amdgcn_mfma_f32_16x16x32_bf16(af[mt], bfr[nt], acc[mt][nt], 0, 0, 0);
    __builtin_amdgcn_s_setprio(0);
  }
}

__global__ __launch_bounds__(512, 2) void gemm_pv2(
    const __bf16* __restrict__ P, const __bf16* __restrict__ vt,
    float* __restrict__ out) {
  __shared__ __align__(16) __bf16 smem[73728];   // 144 KB = 3 x 48 KB buffers
  constexpr int K = 2048;
  const int b    = blockIdx.z;
  const int m0   = blockIdx.x * 256;     // q   (x=q: P-panel XCD locality)
  const int n0   = blockIdx.y * 128;     // dk
  const int wave = threadIdx.x >> 6;
  const int lane = threadIdx.x & 63;
  const int wm   = wave >> 1;            // 0..3
  const int wn   = wave & 1;             // 0..1
  const int sr   = lane >> 2;
  const int scol = ((lane & 3) ^ ((sr >> 1) & 3)) * 8;
  const int frow = lane & 15;
  const int pko  = ((lane >> 4) ^ ((frow >> 1) & 3)) * 8;

  PCtx c;
  c.pA = P + (long)b * Sc * Sc + (long)(m0 + wave * 32 + sr) * K + scol;
  c.pB = vt + (long)b * DKc * Sc + (long)(n0 + wave * 16 + sr) * K + scol;
  c.stA = wave * 1024;
  c.stB = wave * 512;
  c.aoff = (wm * 64 + frow) * 32 + pko;
  c.boff = (wn * 64 + frow) * 32 + pko;

  __bf16* B0 = smem;
  __bf16* B1 = smem + 24576;
  __bf16* B2 = smem + 49152;

  // Prologue (FIFO-order-critical): t0 {A0 x2, B0, A1 x2, B1}, t1 same.
  stage16(c.pA, B0 + c.stA);            stage16(c.pA + 16 * K, B0 + c.stA + 512);
  stage16(c.pB, B0 + 16384 + c.stB);
  stage16(c.pA + 32, B0 + 8192 + c.stA); stage16(c.pA + 32 + 16 * K, B0 + 8192 + c.stA + 512);
  stage16(c.pB + 32, B0 + 20480 + c.stB);
  stage16(c.pA + 64, B1 + c.stA);       stage16(c.pA + 64 + 16 * K, B1 + c.stA + 512);
  stage16(c.pB + 64, B1 + 16384 + c.stB);
  stage16(c.pA + 96, B1 + 8192 + c.stA); stage16(c.pA + 96 + 16 * K, B1 + 8192 + c.stA + 512);
  stage16(c.pB + 96, B1 + 20480 + c.stB);

  floatx4 acc[4][4];
  const floatx4 zero = {0.f, 0.f, 0.f, 0.f};
#pragma unroll
  for (int i = 0; i < 4; ++i)
#pragma unroll
    for (int j = 0; j < 4; ++j) acc[i][j] = zero;

#pragma unroll 1
  for (int t = 0; t < 30; t += 3) {
    tile_step_pv<9, 9, true>(c, t,     B0, B2, acc);
    tile_step_pv<9, 9, true>(c, t + 1, B1, B0, acc);
    tile_step_pv<9, 9, true>(c, t + 2, B2, B1, acc);
  }
  tile_step_pv<9, 6, false>(c, 30, B0, B0, acc);
  tile_step_pv<3, 0, false>(c, 31, B1, B1, acc);

  // ---- epilogue: direct fp32 store ----
  const int crow0 = (lane >> 4) * 4;
  const int ccol  = lane & 15;
#pragma unroll
  for (int nt = 0; nt < 4; ++nt) {
    int cn = n0 + wn * 64 + nt * 16 + ccol;
#pragma unroll
    for (int mt = 0; mt < 4; ++mt) {
#pragma unroll
      for (int r = 0; r < 4; ++r) {
        int cm_ = m0 + wm * 64 + mt * 16 + crow0 + r;
        out[(long)b * Sc * DKc + (long)cm_ * DKc + cn] = acc[mt][nt][r];
      }
    }
  }
}

// ---------------------------------------------------------------------------
// G GEMM, 64x64 tiles (256 blocks). Gt[m][n] = sum_k WK[m,k]WQ[n,k],
// split operands (3 MFMA), hi/lo output.
// ---------------------------------------------------------------------------
__global__ __launch_bounds__(256) void gemm_g64(
    const __bf16* __restrict__ Ahi, const __bf16* __restrict__ Alo,
    const __bf16* __restrict__ Bhi, const __bf16* __restrict__ Blo,
    __bf16* __restrict__ Chi, __bf16* __restrict__ Clo) {
  constexpr int K = Dc, N = DKc;
  __shared__ __align__(16) char smem[16384];
  __bf16* sAh = (__bf16*)smem;           // [64][32]
  __bf16* sBh = sAh + 64 * 32;
  __bf16* sAl = sBh + 64 * 32;
  __bf16* sBl = sAl + 64 * 32;

  const int wave = threadIdx.x >> 6;
  const int lane = threadIdx.x & 63;
  const int wm   = wave >> 1, wn = wave & 1;
  const int m0   = blockIdx.y * 64;
  const int n0   = blockIdx.x * 64;

  const int sr   = lane >> 2;
  const int sc_  = lane & 3;
  const int scol = (sc_ ^ ((sr >> 1) & 3)) * 8;
  const int frow = lane & 15;
  const int pko  = ((lane >> 4) ^ ((frow >> 1) & 3)) * 8;

  floatx4 acc[2][2];
  const floatx4 zero = {0.f, 0.f, 0.f, 0.f};
#pragma unroll
  for (int i = 0; i < 2; ++i)
#pragma unroll
    for (int j = 0; j < 2; ++j) acc[i][j] = zero;

#pragma unroll 1
  for (int k0 = 0; k0 < K; k0 += 32) {
    const int rb = wave * 16;                       // wave stages 16 rows
    const long ga = (long)(m0 + rb + sr) * K + k0 + scol;
    const long gb = (long)(n0 + rb + sr) * K + k0 + scol;
    stage16(Ahi + ga, sAh + rb * 32);
    stage16(Alo + ga, sAl + rb * 32);
    stage16(Bhi + gb, sBh + rb * 32);
    stage16(Blo + gb, sBl + rb * 32);
    __syncthreads();

    bf16x8 af[2], bfr[2], afl[2], bfl[2];
#pragma unroll
    for (int t = 0; t < 2; ++t) {
      af[t]  = *(const bf16x8*)(sAh + (wm * 32 + t * 16 + frow) * 32 + pko);
      bfr[t] = *(const bf16x8*)(sBh + (wn * 32 + t * 16 + frow) * 32 + pko);
      afl[t] = *(const bf16x8*)(sAl + (wm * 32 + t * 16 + frow) * 32 + pko);
      bfl[t] = *(const bf16x8*)(sBl + (wn * 32 + t * 16 + frow) * 32 + pko);
    }
#pragma unroll
    for (int mt = 0; mt < 2; ++mt)
#pragma unroll
      for (int nt = 0; nt < 2; ++nt) {
        acc[mt][nt] = __builtin_amdgcn_mfma_f32_16x16x32_bf16(af[mt], bfr[nt], acc[mt][nt], 0, 0, 0);
        acc[mt][nt] = __builtin_amdgcn_mfma_f32_16x16x32_bf16(af[mt], bfl[nt], acc[mt][nt], 0, 0, 0);
        acc[mt][nt] = __builtin_amdgcn_mfma_f32_16x16x32_bf16(afl[mt], bfr[nt], acc[mt][nt], 0, 0, 0);
      }
    __syncthreads();
  }

  const int crow0 = (lane >> 4) * 4;
  const int ccol  = lane & 15;
  const int tid   = threadIdx.x;
  __bf16* sT = (__bf16*)smem;            // [64][64] = 8KB
#pragma unroll 1
  for (int pass = 0; pass < 2; ++pass) {
    __syncthreads();
#pragma unroll
    for (int nt = 0; nt < 2; ++nt) {
      int col = wn * 32 + nt * 16 + ccol;
#pragma unroll
      for (int mt = 0; mt < 2; ++mt) {
        int row = wm * 32 + mt * 16 + crow0;
#pragma unroll
        for (int r = 0; r < 4; ++r) {
          float v = acc[mt][nt][r];
          __bf16 h = f2bf(v);
          sT[(row + r) * 64 + col] = pass ? f2bf(v - bf2f(h)) : h;
        }
      }
    }
    __syncthreads();
    __bf16* dst = pass ? Clo : Chi;
#pragma unroll
    for (int c = 0; c < 2; ++c) {
      int flat = c * 2048 + tid * 8;
      int row = flat >> 6, col = flat & 63;
      *(bf16x8*)(dst + (long)(m0 + row) * N + n0 + col) = *(const bf16x8*)(sT + flat);
    }
  }
}

// ---------------------------------------------------------------------------
// Fold 8 q-tile partials -> ffac[b][t][k] = exp(M_t - M_k) / Z_k.
// ---------------------------------------------------------------------------
__global__ __launch_bounds__(256) void softmax_reduce(const float* __restrict__ Pmax,
                                                      const float* __restrict__ Psum,
                                                      float* __restrict__ Ffac) {
  int idx = blockIdx.x * 256 + threadIdx.x;   // b*2048 + k
  int b = idx >> 11, k = idx & (Sc - 1);
  const float* pm = Pmax + (long)b * 8 * Sc + k;
  const float* ps = Psum + (long)b * 8 * Sc + k;
  float M = -3.0e38f;
#pragma unroll
  for (int t = 0; t < 8; ++t) M = fmaxf(M, pm[(long)t * Sc]);
  float S = 0.f;
#pragma unroll
  for (int t = 0; t < 8; ++t)
    S += ps[(long)t * Sc] * __expf(pm[(long)t * Sc] - M);
  float inv = 1.0f / S;
  float* fo = Ffac + (long)b * 8 * Sc + k;
#pragma unroll
  for (int t = 0; t < 8; ++t)
    fo[(long)t * Sc] = __expf(pm[(long)t * Sc] - M) * inv;
}

// ---------------------------------------------------------------------------
extern "C" void kernel_launch(void* const* d_in, const int* in_sizes, int n_in,
                              void* d_out, int out_size, void* d_ws, size_t ws_size,
                              hipStream_t stream) {
  const float* x  = (const float*)d_in[0];
  const float* WQ = (const float*)d_in[1];
  const float* WK = (const float*)d_in[2];
  const float* WV = (const float*)d_in[3];
  float* out = (float*)d_out;
  char* ws = (char*)d_ws;
  const long MB = 1024L * 1024L;

  // Workspace layout (peak ~131 MB).
  __bf16* xhi  = (__bf16*)(ws + 0 * MB);     // 16 MB
  __bf16* xlo  = (__bf16*)(ws + 16 * MB);    // 16 MB
  __bf16* wqhi = (__bf16*)(ws + 32 * MB);    // 2 MB each (element-wise split)
  __bf16* wqlo = (__bf16*)(ws + 34 * MB);
  __bf16* wkhi = (__bf16*)(ws + 36 * MB);
  __bf16* wklo = (__bf16*)(ws + 38 * MB);
  __bf16* wvthi= (__bf16*)(ws + 40 * MB);    // transposed, hi only
  __bf16* gthi = (__bf16*)(ws + 44 * MB);    // 2 MB each: Gt = (WQ WK^T)^T
  __bf16* gtlo = (__bf16*)(ws + 46 * MB);
  __bf16* thi  = (__bf16*)(ws + 48 * MB);    // 16 MB each: T = x*G
  __bf16* tlo  = (__bf16*)(ws + 64 * MB);
  __bf16* vt   = (__bf16*)(ws + 80 * MB);    // 16 MB, [B][DK][S]
  __bf16* P    = (__bf16*)(ws + 96 * MB);    // 32 MB, p = exp(s - M_t), bf16
  float*  pmax = (float*)(ws + 128 * MB);    // [B][8][S]
  float*  psum = (float*)(ws + 129 * MB);
  float*  ffac = (float*)(ws + 130 * MB);    // [B][8][S]

  // 1. casts + WV transpose (one dispatch)
  prep<<<41984, 256, 0, stream>>>(x, xhi, xlo, WQ, wqhi, wqlo, WK, wkhi, wklo,
                                  WV, wvthi);

  // 2. Gt[d][a] = G[a][d]: NT(A=WK, B=WQ), 64x64 tiles -> 256 blocks.
  gemm_g64<<<dim3(16, 16), 256, 0, stream>>>(wkhi, wklo, wqhi, wqlo, gthi, gtlo);

  // 3. T = x*G (split) -- 3-phase pipelined 256x128 tiles, 256 blocks.
  gemm_t2<<<dim3(DKc / 128, BSc / 256, 1), 512, 0, stream>>>(
      xhi, xlo, gthi, gtlo, thi, tlo);

  // 4. Vt = (x*WV)^T per batch (plain).
  gemm_v<<<dim3(DKc / 128, BSc / 128, 1), 256, 0, stream>>>(xhi, wvthi, vt);

  // 5. S = T*x^T * scale; emits p (bf16) + per-256-tile column max/expsum.
  gemm_s2<<<dim3(Sc / 256, Sc / 256, Bc), 512, 0, stream>>>(
      thi, tlo, xhi, xlo, P, pmax, psum);

  // 6. partials -> ffac (8 q-tiles)
  softmax_reduce<<<32, 256, 0, stream>>>(pmax, psum, ffac);

  // 7. P <- P .* ffac (elementwise; the old gemm_pv A-staging multiply).
  scale_p<<<8192, 256, 0, stream>>>(P, ffac);

  // 8. out = P @ Vt^T -- plain 2-phase/3-buffer counted-vmcnt pipeline.
  gemm_pv2<<<dim3(Sc / 256, DKc / 128, Bc), 512, 0, stream>>>(P, vt, out);
}